// Round 6
// baseline (15519.553 us; speedup 1.0000x reference)
//
#include <hip/hip_runtime.h>
#include <hip/hip_bf16.h>
#include <math.h>

typedef unsigned short u16;
typedef unsigned int u32;
typedef __attribute__((ext_vector_type(8))) __bf16 bf16x8;
typedef __attribute__((ext_vector_type(4))) float f32x4;

#define LSTM_L 200
#define LSTM_B 2048
#define LSTM_HIN 64
#define LSTM_H 256
#define NCLUST 64
#define HALF_BETA 0.05f

// LDS: sh0 8KB | sh1 8KB | W1-cache (ch0,1 all 32 slices) 128KB
#define LDS_BYTES (8192 + 8192 + 131072)

__device__ __forceinline__ void gload_lds16(const void* g, void* l) {
    __builtin_amdgcn_global_load_lds(
        (__attribute__((address_space(1))) const void*)g,
        (__attribute__((address_space(3))) void*)l, 16, 0, 0);
}

__device__ __forceinline__ float fast_sigmoid(float x) {
    return __builtin_amdgcn_rcpf(1.f + __expf(-x));
}
__device__ __forceinline__ float fast_tanh(float x) {
    return 2.f * __builtin_amdgcn_rcpf(1.f + __expf(-2.f * x)) - 1.f;
}

// ---------------------------------------------------------------------------
// Weight pack into per-(nb,wn) fragment order (same layout as rounds 4/5):
// elem i = ((((nb*4+wn)*NCH + ch)*2 + nf)*64 + lane)*8 + e
// j = (2*nf + (l15&1))*256 + nb*32 + wn*8 + (l15>>1); k = ch*32 + (lane>>4)*8 + e
// ---------------------------------------------------------------------------
template<int KIN>
__global__ __launch_bounds__(256) void pack_frag(
    const float* __restrict__ Wih, const float* __restrict__ Whh,
    u16* __restrict__ Wp)
{
    constexpr int NCH = (KIN + LSTM_H) / 32;
    const int total = 1024 * (KIN + LSTM_H);
    for (int i = blockIdx.x * 256 + threadIdx.x; i < total; i += gridDim.x * 256) {
        const int e = i & 7;
        int t = i >> 3;
        const int lane = t & 63; t >>= 6;
        const int nf = t & 1;    t >>= 1;
        const int ch = t % NCH;  t /= NCH;
        const int wn = t & 3;
        const int nb = t >> 2;
        const int l15 = lane & 15;
        const int j = (2 * nf + (l15 & 1)) * 256 + nb * 32 + wn * 8 + (l15 >> 1);
        const int k = ch * 32 + ((lane >> 4) << 3) + e;
        const float v = (k < KIN) ? Wih[(size_t)j * KIN + k]
                                  : Whh[(size_t)j * LSTM_H + (k - KIN)];
        Wp[i] = __builtin_bit_cast(u16, (__bf16)v);
    }
}

// ---------------------------------------------------------------------------
// Zero-sync persistent LSTM: 128 independent blocks x 16 batch rows each.
// Each block runs ALL 200 steps of BOTH layers for its rows; weights are
// streamed from L2 every step (frag-packed, contiguous 16B/lane loads);
// h0/h1 in swizzled LDS (8KB each); c0/c1 in registers for the whole
// sequence. No grid syncs, no fences, no global h traffic. 8 waves: wave w
// owns h-cols w*32..w*32+31 (x4 gates), wn-subslices of 8 cols.
// ---------------------------------------------------------------------------
__device__ __forceinline__ void lstm_pw(
    const f32x4& accA, const f32x4& accB, float c[4],
    float bA, float bB, int gpar, int q, int w, int wn, int l15,
    char* shdst, float* latdst, int r0)
{
#pragma unroll
    for (int r = 0; r < 4; ++r) {
        const float a0v = accA[r] + bA;
        const float a1v = accB[r] + bB;
        const float p0 = __shfl_xor(a0v, 1);
        const float p1 = __shfl_xor(a1v, 1);
        const float gi = gpar ? p0 : a0v;
        const float gf = gpar ? a0v : p0;
        const float gg = gpar ? p1 : a1v;
        const float go = gpar ? a1v : p1;
        const float cn = fast_sigmoid(gf) * c[r] + fast_sigmoid(gi) * fast_tanh(gg);
        c[r] = cn;
        const float hv = fast_sigmoid(go) * fast_tanh(cn);
        const int row = q * 4 + r;
        if (latdst) {
            if (!gpar)
                latdst[(size_t)(r0 + row) * 256 + (w * 32 + wn * 8 + (l15 >> 1))] = hv;
        } else {
            const u16 hb = __builtin_bit_cast(u16, (__bf16)hv);
            const u32 partner = (u32)(u16)__shfl_xor((int)hb, 2);
            const u32 pk = (u32)hb | (partner << 16);
            if ((l15 & 3) == 0) {
                const int p = l15 >> 2;
                const int boff = (w * 64 + wn * 16 + p * 4) ^ ((row & 7) << 4);
                *(u32*)(shdst + row * 512 + boff) = pk;
            }
        }
    }
}

__global__ __launch_bounds__(512, 1) void lstm_stream(
    const float* __restrict__ X,
    const u16* __restrict__ Wp0, const u16* __restrict__ Wp1,
    const float* __restrict__ bih0, const float* __restrict__ bhh0,
    const float* __restrict__ bih1, const float* __restrict__ bhh1,
    float* __restrict__ latent)
{
    extern __shared__ char smem[];
    char* sh0 = smem;                  // [16 rows][512B], XOR-swizzled
    char* sh1 = smem + 8192;
    u16*  sWc = (u16*)(smem + 16384);  // W1 cache: 32 slices x 2048 u16 (ch0,1)

    const int tid = threadIdx.x;
    const int lane = tid & 63;
    const int w = tid >> 6;            // wave 0..7 = h-col slice
    const int l15 = lane & 15;
    const int q = lane >> 4;
    const int gpar = l15 & 1;
    const int r0 = (int)blockIdx.x * 16;
    const int swzl = (l15 & 7) << 4;

    // ---- init: zero h buffers; cache W1 ch0,1 (4KB per slice) into LDS ----
    for (int i = tid; i < 4096; i += 512) ((int*)smem)[i] = 0;
    for (int i = tid; i < 8192; i += 512) {
        const int sl = i >> 8;         // slice 0..31
        const int wi = i & 255;        // 16B chunk within slice's 4KB
        gload_lds16(Wp1 + (size_t)sl * 16384 + wi * 8, sWc + (size_t)i * 8);
    }

    // ---- per-(wn,parity) biases ----
    float bA0[4], bB0[4], bA1[4], bB1[4];
#pragma unroll
    for (int wn = 0; wn < 4; ++wn) {
        const int hcol = w * 32 + wn * 8 + (l15 >> 1);
        bA0[wn] = bih0[gpar * 256 + hcol] + bhh0[gpar * 256 + hcol];
        bB0[wn] = bih0[(2 + gpar) * 256 + hcol] + bhh0[(2 + gpar) * 256 + hcol];
        bA1[wn] = bih1[gpar * 256 + hcol] + bhh1[gpar * 256 + hcol];
        bB1[wn] = bih1[(2 + gpar) * 256 + hcol] + bhh1[(2 + gpar) * 256 + hcol];
    }

    float c0[4][4], c1[4][4];
#pragma unroll
    for (int wn = 0; wn < 4; ++wn)
#pragma unroll
        for (int r = 0; r < 4; ++r) { c0[wn][r] = 0.f; c1[wn][r] = 0.f; }

    const u16* wp0base = Wp0 + (size_t)(w * 4) * 10 * 1024 + lane * 8;
    const u16* wp1base = Wp1 + (size_t)(w * 4) * 16 * 1024 + lane * 8;

    __syncthreads();

    for (int s = 0; s < LSTM_L; ++s) {
        // ---- (A) read all A-fragments that reference h0_prev / h1_prev ----
        bf16x8 a0[10], a1s[8];
        {
            const float* xs = X + (size_t)s * LSTM_B * LSTM_HIN
                                + (size_t)(r0 + l15) * LSTM_HIN + q * 8;
#pragma unroll
            for (int ch = 0; ch < 2; ++ch) {
                const float4 v0 = *(const float4*)(xs + ch * 32);
                const float4 v1 = *(const float4*)(xs + ch * 32 + 4);
                bf16x8 pk;
                pk[0] = (__bf16)v0.x; pk[1] = (__bf16)v0.y;
                pk[2] = (__bf16)v0.z; pk[3] = (__bf16)v0.w;
                pk[4] = (__bf16)v1.x; pk[5] = (__bf16)v1.y;
                pk[6] = (__bf16)v1.z; pk[7] = (__bf16)v1.w;
                a0[ch] = pk;
            }
        }
#pragma unroll
        for (int f = 0; f < 8; ++f)
            a0[2 + f] = *(const bf16x8*)(sh0 + l15 * 512 + ((f * 64 + q * 16) ^ swzl));
#pragma unroll
        for (int f = 0; f < 8; ++f)
            a1s[f] = *(const bf16x8*)(sh1 + l15 * 512 + ((f * 64 + q * 16) ^ swzl));
        __syncthreads();   // (B) all h_prev reads done

        // ---- (C) layer 0: stream W0, MFMA, pointwise, write h0_new ----
#pragma unroll
        for (int wn = 0; wn < 4; ++wn) {
            const u16* wp = wp0base + (size_t)wn * 10240;
            f32x4 accA = {0.f, 0.f, 0.f, 0.f};
            f32x4 accB = {0.f, 0.f, 0.f, 0.f};
#pragma unroll
            for (int ch = 0; ch < 10; ++ch) {
                const bf16x8 b0 = *(const bf16x8*)(wp + ch * 1024);
                const bf16x8 b1 = *(const bf16x8*)(wp + ch * 1024 + 512);
                accA = __builtin_amdgcn_mfma_f32_16x16x32_bf16(a0[ch], b0, accA, 0, 0, 0);
                accB = __builtin_amdgcn_mfma_f32_16x16x32_bf16(a0[ch], b1, accB, 0, 0, 0);
            }
            lstm_pw(accA, accB, c0[wn], bA0[wn], bB0[wn], gpar, q, w, wn, l15,
                    sh0, nullptr, r0);
        }
        __syncthreads();   // (D) h0_new visible

        // ---- (E) layer 1: cached ch0,1 from LDS + stream ch2..15 ----
        bf16x8 a1l[8];
#pragma unroll
        for (int f = 0; f < 8; ++f)
            a1l[f] = *(const bf16x8*)(sh0 + l15 * 512 + ((f * 64 + q * 16) ^ swzl));
        float* latdst = (s == LSTM_L - 1) ? latent : nullptr;
#pragma unroll
        for (int wn = 0; wn < 4; ++wn) {
            const u16* wp = wp1base + (size_t)wn * 16384;
            const u16* cw = sWc + (w * 4 + wn) * 2048 + lane * 8;
            f32x4 accA = {0.f, 0.f, 0.f, 0.f};
            f32x4 accB = {0.f, 0.f, 0.f, 0.f};
#pragma unroll
            for (int ch = 0; ch < 2; ++ch) {
                const bf16x8 b0 = *(const bf16x8*)(cw + ch * 1024);
                const bf16x8 b1 = *(const bf16x8*)(cw + ch * 1024 + 512);
                accA = __builtin_amdgcn_mfma_f32_16x16x32_bf16(a1l[ch], b0, accA, 0, 0, 0);
                accB = __builtin_amdgcn_mfma_f32_16x16x32_bf16(a1l[ch], b1, accB, 0, 0, 0);
            }
#pragma unroll
            for (int ch = 2; ch < 16; ++ch) {
                const bf16x8 b0 = *(const bf16x8*)(wp + ch * 1024);
                const bf16x8 b1 = *(const bf16x8*)(wp + ch * 1024 + 512);
                const bf16x8 a = (ch < 8) ? a1l[ch] : a1s[ch - 8];
                accA = __builtin_amdgcn_mfma_f32_16x16x32_bf16(a, b0, accA, 0, 0, 0);
                accB = __builtin_amdgcn_mfma_f32_16x16x32_bf16(a, b1, accB, 0, 0, 0);
            }
            lstm_pw(accA, accB, c1[wn], bA1[wn], bB1[wn], gpar, q, w, wn, l15,
                    sh1, latdst, r0);
        }
        __syncthreads();   // (F) h1_new visible for next iteration
    }
}

// ---------------------------------------------------------------------------
// K-means tail (round-5 versions: atomic accumulate, trivial finalize)
// ---------------------------------------------------------------------------
__global__ __launch_bounds__(64) void assign_accum(
    const float* __restrict__ lat, const float* __restrict__ clusters,
    int* __restrict__ ids, float* __restrict__ sums, int* __restrict__ counts)
{
    __shared__ float row[LSTM_H];
    const int b = blockIdx.x;
    const int k = threadIdx.x;
    for (int i = k; i < LSTM_H; i += 64) row[i] = lat[(size_t)b * LSTM_H + i];
    __syncthreads();
    const float* ck = clusters + (size_t)k * LSTM_H;
    float d = 0.f;
#pragma unroll 8
    for (int i = 0; i < LSTM_H; ++i) { const float t = row[i] - ck[i]; d += t * t; }
    int idx = k;
    for (int off = 32; off > 0; off >>= 1) {
        const float od = __shfl_down(d, off, 64);
        const int   oi = __shfl_down(idx, off, 64);
        if (od < d || (od == d && oi < idx)) { d = od; idx = oi; }
    }
    const int best = __shfl(idx, 0, 64);
    if (k == 0) { ids[b] = best; atomicAdd(&counts[best], 1); }
#pragma unroll
    for (int j = 0; j < 4; ++j)
        atomicAdd(&sums[(size_t)best * LSTM_H + k * 4 + j], row[k * 4 + j]);
}

__global__ __launch_bounds__(256) void centroid_final(
    const float* __restrict__ sums, const int* __restrict__ counts,
    const float* __restrict__ clusters, float* __restrict__ upd)
{
    const int k = blockIdx.x;
    const int h = threadIdx.x;
    const int c = counts[k];
    upd[(size_t)k * LSTM_H + h] = (c > 0)
        ? sums[(size_t)k * LSTM_H + h] / (float)c
        : clusters[(size_t)k * LSTM_H + h];
}

__global__ __launch_bounds__(256) void loss_kernel(
    const float* __restrict__ lat, const int* __restrict__ ids,
    const float* __restrict__ upd, float* __restrict__ out_loss)
{
    float p = 0.f;
    const int total = LSTM_B * LSTM_H;
    for (int idx = blockIdx.x * blockDim.x + threadIdx.x; idx < total;
         idx += gridDim.x * blockDim.x) {
        const int b = idx >> 8;
        const float d = lat[idx] - upd[(size_t)ids[b] * LSTM_H + (idx & 255)];
        p += d * d;
    }
    for (int off = 32; off > 0; off >>= 1) p += __shfl_down(p, off, 64);
    __shared__ float wsum[4];
    const int lane = threadIdx.x & 63, wid = threadIdx.x >> 6;
    if (lane == 0) wsum[wid] = p;
    __syncthreads();
    if (threadIdx.x == 0)
        atomicAdd(out_loss, HALF_BETA * (wsum[0] + wsum[1] + wsum[2] + wsum[3]));
}

// ---------------------------------------------------------------------------
extern "C" void kernel_launch(void* const* d_in, const int* in_sizes, int n_in,
                              void* d_out, int out_size, void* d_ws, size_t ws_size,
                              hipStream_t stream)
{
    const float* X     = (const float*)d_in[0];
    const float* Wih0  = (const float*)d_in[1];
    const float* Whh0  = (const float*)d_in[2];
    const float* bih0  = (const float*)d_in[3];
    const float* bhh0  = (const float*)d_in[4];
    const float* Wih1  = (const float*)d_in[5];
    const float* Whh1  = (const float*)d_in[6];
    const float* bih1  = (const float*)d_in[7];
    const float* bhh1  = (const float*)d_in[8];
    const float* clust = (const float*)d_in[9];

    float* out = (float*)d_out;
    char* base = (char*)d_ws;
    const size_t MB = 1u << 20;
    const size_t KB = 1024;

    u16* Wp0    = (u16*)(base + 0 * MB);              // 640 KB
    u16* Wp1    = (u16*)(base + 1 * MB);              // 1 MB
    float* sums = (float*)(base + 2 * MB);            // 64 KB
    float* upd  = (float*)(base + 2 * MB + 64 * KB);  // 64 KB
    int* counts = (int*)(base + 2 * MB + 128 * KB);   // 256 B
    int* ids    = (int*)(base + 2 * MB + 132 * KB);   // 8 KB

    const size_t BH = (size_t)LSTM_B * LSTM_H;

    // zero: k-means scratch + loss slot (h/c live entirely on-chip now)
    hipMemsetAsync(base + 2 * MB, 0, 132 * KB, stream);
    hipMemsetAsync(out + BH, 0, sizeof(float), stream);

    pack_frag<LSTM_HIN><<<320, 256, 0, stream>>>(Wih0, Whh0, Wp0);
    pack_frag<LSTM_H>  <<<512, 256, 0, stream>>>(Wih1, Whh1, Wp1);

    hipFuncSetAttribute((const void*)lstm_stream,
                        hipFuncAttributeMaxDynamicSharedMemorySize, LDS_BYTES);

    lstm_stream<<<128, 512, LDS_BYTES, stream>>>(
        X, Wp0, Wp1, bih0, bhh0, bih1, bhh1, out);

    assign_accum<<<LSTM_B, 64, 0, stream>>>(out, clust, ids, sums, counts);
    centroid_final<<<NCLUST, 256, 0, stream>>>(sums, counts, clust, upd);
    loss_kernel<<<256, 256, 0, stream>>>(out, ids, upd, out + BH);
}

// Round 8
// 5055.852 us; speedup vs baseline: 3.0696x; 3.0696x over previous
//
#include <hip/hip_runtime.h>
#include <hip/hip_bf16.h>
#include <math.h>

typedef unsigned short u16;
typedef unsigned int u32;
typedef __attribute__((ext_vector_type(8))) __bf16 bf16x8;
typedef __attribute__((ext_vector_type(4))) float f32x4;

#define LSTM_L 200
#define LSTM_B 2048
#define LSTM_HIN 64
#define LSTM_H 256
#define NCLUST 64
#define HALF_BETA 0.05f
#define LDS_BYTES 131072

__device__ __forceinline__ float fast_sigmoid(float x) {
    return __builtin_amdgcn_rcpf(1.f + __expf(-x));
}
__device__ __forceinline__ float fast_tanh(float x) {
    return 2.f * __builtin_amdgcn_rcpf(1.f + __expf(-2.f * x)) - 1.f;
}

__device__ __forceinline__ u32 cload(const u32* p) {     // coherent (L2-bypass) load
    return __hip_atomic_load(p, __ATOMIC_RELAXED, __HIP_MEMORY_SCOPE_AGENT);
}
__device__ __forceinline__ void cstore(u32* p, u32 v) {  // coherent write-through store
    __hip_atomic_store(p, v, __ATOMIC_RELAXED, __HIP_MEMORY_SCOPE_AGENT);
}
// Bounded spin: tid==0 only. A wedged protocol becomes a wrong answer
// (bench-visible), never a hung container.
__device__ __forceinline__ void spin_ge(u32* p, u32 target) {
    int guard = 0;
    while (cload(p) < target) {
        __builtin_amdgcn_s_sleep(8);
        if (++guard > (1 << 18)) break;   // ~55 ms cap
    }
}

// ---------------------------------------------------------------------------
// Weight pack into per-(nb,wn) fragment order (round-4/5 layout):
// elem i = ((((nb*4+wn)*NCH + ch)*2 + nf)*64 + lane)*8 + e
// j = (2*nf + (l15&1))*256 + nb*32 + wn*8 + (l15>>1); k = ch*32 + (lane>>4)*8 + e
// ---------------------------------------------------------------------------
template<int KIN>
__global__ __launch_bounds__(256) void pack_frag(
    const float* __restrict__ Wih, const float* __restrict__ Whh,
    u16* __restrict__ Wp)
{
    constexpr int NCH = (KIN + LSTM_H) / 32;
    const int total = 1024 * (KIN + LSTM_H);
    for (int i = blockIdx.x * 256 + threadIdx.x; i < total; i += gridDim.x * 256) {
        const int e = i & 7;
        int t = i >> 3;
        const int lane = t & 63; t >>= 6;
        const int nf = t & 1;    t >>= 1;
        const int ch = t % NCH;  t /= NCH;
        const int wn = t & 3;
        const int nb = t >> 2;
        const int l15 = lane & 15;
        const int j = (2 * nf + (l15 & 1)) * 256 + nb * 32 + wn * 8 + (l15 >> 1);
        const int k = ch * 32 + ((lane >> 4) << 3) + e;
        const float v = (k < KIN) ? Wih[(size_t)j * KIN + k]
                                  : Whh[(size_t)j * LSTM_H + (k - KIN)];
        Wp[i] = __builtin_bit_cast(u16, (__bf16)v);
    }
}

// ---------------------------------------------------------------------------
// Pointwise epilogue: gates via shfl_xor(1); h packed to u32 (col pairs via
// shfl_xor(2)) written with coherent stores, or f32 latent at the final slot.
// ---------------------------------------------------------------------------
__device__ __forceinline__ void pw_emit(
    f32x4 (&acc)[4][2], float (&cp)[4][4], float bA, float bB,
    int gpar, int q, int l15, int brow, int hcol, int nb, int wn,
    u32* hdst, float* latdst)
{
#pragma unroll
    for (int mf = 0; mf < 4; ++mf) {
#pragma unroll
        for (int r = 0; r < 4; ++r) {
            const int rowo = brow + mf * 16 + q * 4 + r;
            const float a0v = acc[mf][0][r] + bA;
            const float a1v = acc[mf][1][r] + bB;
            const float p0 = __shfl_xor(a0v, 1);
            const float p1 = __shfl_xor(a1v, 1);
            const float gi = gpar ? p0 : a0v;
            const float gf = gpar ? a0v : p0;
            const float gg = gpar ? p1 : a1v;
            const float go = gpar ? a1v : p1;
            const float cn = fast_sigmoid(gf) * cp[mf][r]
                           + fast_sigmoid(gi) * fast_tanh(gg);
            cp[mf][r] = cn;
            const float hv = fast_sigmoid(go) * fast_tanh(cn);
            if (latdst) {
                if (!gpar) latdst[(size_t)rowo * 256 + hcol] = hv;
            } else {
                const u16 hb = __builtin_bit_cast(u16, (__bf16)hv);
                const int pr = __shfl_xor((int)(u32)hb, 2);
                const u32 pk = ((u32)hb & 0xffffu) | (((u32)pr) << 16);
                if ((l15 & 3) == 0)
                    cstore(hdst + (size_t)rowo * 128 + nb * 16 + wn * 4 + (l15 >> 2), pk);
            }
        }
    }
}

// ---------------------------------------------------------------------------
// Persistent flag-synced LSTM, NO FENCES. 256 blocks = 16 groups (mb) x
// {8 L0-blocks + 8 L1-blocks}. Weights in VGPRs (loaded once). Per step:
// coherent u32 loads stage h into frag-major LDS; conflict-free ds_read_b128
// feeds MFMA; c-state lives in registers across all 200 steps.
// cnt0/cnt1[mb]: ONE increment per block per step (8/step/group).
// Waits: L0@s needs cnt0>=8s, cnt1>=8(s-1); L1@s needs cnt0>=8s, cnt1>=8(s-1).
// Spin is tid==0 only + __syncthreads broadcast (round-5 proven pattern).
// ---------------------------------------------------------------------------
__global__ __launch_bounds__(512, 1) void lstm_persist3(
    const float* __restrict__ X,
    const u16* __restrict__ Wp0, const u16* __restrict__ Wp1,
    const float* __restrict__ bih0, const float* __restrict__ bhh0,
    const float* __restrict__ bih1, const float* __restrict__ bhh1,
    u32* h0b0, u32* h0b1, u32* h1b0, u32* h1b1,
    float* __restrict__ latent, u32* cnt0, u32* cnt1)
{
    extern __shared__ char smem[];
    const int tid = threadIdx.x;
    const int lane = tid & 63;
    const int w = tid >> 6;
    const int wm = w >> 2;
    const int wn = w & 3;
    const int l15 = lane & 15;
    const int q = lane >> 4;
    const int gpar = l15 & 1;
    const int bi = (int)blockIdx.x;
    const int mb = bi & 15;          // all 16 blocks of a group share bi%16
    const int layer = (bi >> 4) & 1;
    const int nb = bi >> 5;
    const int b0 = mb * 128;
    u32* c0p = cnt0 + mb * 32;       // distinct cachelines per group
    u32* c1p = cnt1 + mb * 32;

    const int hcol = nb * 32 + wn * 8 + (l15 >> 1);
    const int brow = b0 + wm * 64;

    float cp[4][4];
#pragma unroll
    for (int mf = 0; mf < 4; ++mf)
#pragma unroll
        for (int r = 0; r < 4; ++r) cp[mf][r] = 0.f;

    u32* h0b[2] = {h0b0, h0b1};
    u32* h1b[2] = {h1b0, h1b1};

    if (layer == 0) {
        // ---------------- LAYER 0 ----------------
        bf16x8 Breg[10][2];
        {
            const u16* wp = Wp0 + (size_t)((nb * 4 + wn) * 10) * 1024 + lane * 8;
#pragma unroll
            for (int ch = 0; ch < 10; ++ch)
#pragma unroll
                for (int nf = 0; nf < 2; ++nf)
                    Breg[ch][nf] = *(const bf16x8*)(wp + (ch * 2 + nf) * 512);
        }
        const float bA = bih0[gpar * 256 + hcol] + bhh0[gpar * 256 + hcol];
        const float bB = bih0[(2 + gpar) * 256 + hcol] + bhh0[(2 + gpar) * 256 + hcol];

        for (int s = 0; s < LSTM_L; ++s) {
            // prefetch X (normal HBM loads) before the wait
            float4 xv[2][2];
#pragma unroll
            for (int p = 0; p < 2; ++p) {
                const int idx = p * 512 + tid;       // 1024 x-fraglets
                const int F = idx >> 6;              // ch = F>>3 in {0,1}
                const int sl = idx & 63;
                const int row = (F & 7) * 16 + (sl & 15);
                const float* sp = X + (size_t)s * LSTM_B * LSTM_HIN
                                  + (size_t)(b0 + row) * 64 + (F >> 3) * 32 + (sl >> 4) * 8;
                xv[p][0] = *(const float4*)sp;
                xv[p][1] = *(const float4*)(sp + 4);
            }
            if (tid == 0) {
                if (s >= 1) spin_ge(c0p, 8u * s);
                if (s >= 2) spin_ge(c1p, 8u * (s - 1));
            }
            __syncthreads();   // broadcast flag state; also guards smem reuse

            // stage x frags (F 0..15)
#pragma unroll
            for (int p = 0; p < 2; ++p) {
                const int idx = p * 512 + tid;
                bf16x8 pk;
                pk[0] = (__bf16)xv[p][0].x; pk[1] = (__bf16)xv[p][0].y;
                pk[2] = (__bf16)xv[p][0].z; pk[3] = (__bf16)xv[p][0].w;
                pk[4] = (__bf16)xv[p][1].x; pk[5] = (__bf16)xv[p][1].y;
                pk[6] = (__bf16)xv[p][1].z; pk[7] = (__bf16)xv[p][1].w;
                *(bf16x8*)(smem + (size_t)idx * 16) = pk;  // F*1024+sl*16 == idx*16
            }
            // stage h0^{s-1} via coherent loads (frag F = 16 + F', ch' 0..7)
            const u32* hp = h0b[(s + 1) & 1];
#pragma unroll 4
            for (int i = 0; i < 8; ++i) {
                const int idx = i * 512 + tid;       // 4096 fraglets
                const int F = idx >> 6;              // 0..63: ch'=F>>3, r16=F&7
                const int sl = idx & 63;
                const int row = (F & 7) * 16 + (sl & 15);
                const u32* sp = hp + (size_t)(b0 + row) * 128 + (F >> 3) * 16 + (sl >> 4) * 4;
                uint4 v;
                v.x = cload(sp + 0); v.y = cload(sp + 1);
                v.z = cload(sp + 2); v.w = cload(sp + 3);
                *(uint4*)(smem + (size_t)(F + 16) * 1024 + sl * 16) = v;
            }
            __syncthreads();

            f32x4 acc[4][2];
#pragma unroll
            for (int mf = 0; mf < 4; ++mf)
#pragma unroll
                for (int nf = 0; nf < 2; ++nf) acc[mf][nf] = f32x4{0.f,0.f,0.f,0.f};
#pragma unroll
            for (int ch = 0; ch < 10; ++ch) {
                bf16x8 af[4];
#pragma unroll
                for (int mf = 0; mf < 4; ++mf)
                    af[mf] = *(const bf16x8*)(smem +
                        (size_t)(ch * 8 + wm * 4 + mf) * 1024 + lane * 16);
#pragma unroll
                for (int mf = 0; mf < 4; ++mf)
#pragma unroll
                    for (int nf = 0; nf < 2; ++nf)
                        acc[mf][nf] = __builtin_amdgcn_mfma_f32_16x16x32_bf16(
                            af[mf], Breg[ch][nf], acc[mf][nf], 0, 0, 0);
            }

            pw_emit(acc, cp, bA, bB, gpar, q, l15, brow, hcol, nb, wn,
                    h0b[s & 1], nullptr);
            __syncthreads();   // implicit vmcnt(0) at entry: all waves' stores drained
            if (tid == 0)
                __hip_atomic_fetch_add(c0p, 1, __ATOMIC_RELAXED,
                                       __HIP_MEMORY_SCOPE_AGENT);
        }
    } else {
        // ---------------- LAYER 1 ----------------
        bf16x8 Breg[16][2];
        {
            const u16* wp = Wp1 + (size_t)((nb * 4 + wn) * 16) * 1024 + lane * 8;
#pragma unroll
            for (int ch = 0; ch < 16; ++ch)
#pragma unroll
                for (int nf = 0; nf < 2; ++nf)
                    Breg[ch][nf] = *(const bf16x8*)(wp + (ch * 2 + nf) * 512);
        }
        const float bA = bih1[gpar * 256 + hcol] + bhh1[gpar * 256 + hcol];
        const float bB = bih1[(2 + gpar) * 256 + hcol] + bhh1[(2 + gpar) * 256 + hcol];

        for (int s = 1; s <= LSTM_L; ++s) {
            if (tid == 0) {
                spin_ge(c0p, 8u * s);
                if (s >= 2) spin_ge(c1p, 8u * (s - 1));
            }
            __syncthreads();

            const u32* hp0 = h0b[(s - 1) & 1];   // h0^{s-1}
            const u32* hp1 = h1b[s & 1];         // h1^{s-2}
#pragma unroll 4
            for (int i = 0; i < 16; ++i) {
                const int idx = i * 512 + tid;   // 8192 fraglets
                const int F = idx >> 6;          // 0..127: ch=F>>3, r16=F&7
                const int sl = idx & 63;
                const int ch = F >> 3;
                const int row = (F & 7) * 16 + (sl & 15);
                const u32* sp = ((ch < 8) ? hp0 : hp1)
                              + (size_t)(b0 + row) * 128 + (ch & 7) * 16 + (sl >> 4) * 4;
                uint4 v;
                v.x = cload(sp + 0); v.y = cload(sp + 1);
                v.z = cload(sp + 2); v.w = cload(sp + 3);
                *(uint4*)(smem + (size_t)F * 1024 + sl * 16) = v;
            }
            __syncthreads();

            f32x4 acc[4][2];
#pragma unroll
            for (int mf = 0; mf < 4; ++mf)
#pragma unroll
                for (int nf = 0; nf < 2; ++nf) acc[mf][nf] = f32x4{0.f,0.f,0.f,0.f};
#pragma unroll
            for (int ch = 0; ch < 16; ++ch) {
                bf16x8 af[4];
#pragma unroll
                for (int mf = 0; mf < 4; ++mf)
                    af[mf] = *(const bf16x8*)(smem +
                        (size_t)(ch * 8 + wm * 4 + mf) * 1024 + lane * 16);
#pragma unroll
                for (int mf = 0; mf < 4; ++mf)
#pragma unroll
                    for (int nf = 0; nf < 2; ++nf)
                        acc[mf][nf] = __builtin_amdgcn_mfma_f32_16x16x32_bf16(
                            af[mf], Breg[ch][nf], acc[mf][nf], 0, 0, 0);
            }

            pw_emit(acc, cp, bA, bB, gpar, q, l15, brow, hcol, nb, wn,
                    h1b[(s - 1) & 1], (s == LSTM_L) ? latent : nullptr);
            __syncthreads();   // drain all waves' coherent stores
            if (tid == 0 && s < LSTM_L)
                __hip_atomic_fetch_add(c1p, 1, __ATOMIC_RELAXED,
                                       __HIP_MEMORY_SCOPE_AGENT);
        }
    }
}

// ---------------------------------------------------------------------------
// K-means tail: assign + atomic accumulation, finalize, loss.
// ---------------------------------------------------------------------------
__global__ __launch_bounds__(64) void assign_accum(
    const float* __restrict__ lat, const float* __restrict__ clusters,
    int* __restrict__ ids, float* __restrict__ sums, int* __restrict__ counts)
{
    __shared__ float row[LSTM_H];
    const int b = blockIdx.x;
    const int k = threadIdx.x;
    for (int i = k; i < LSTM_H; i += 64) row[i] = lat[(size_t)b * LSTM_H + i];
    __syncthreads();
    const float* ck = clusters + (size_t)k * LSTM_H;
    float d = 0.f;
#pragma unroll 8
    for (int i = 0; i < LSTM_H; ++i) { const float t = row[i] - ck[i]; d += t * t; }
    int idx = k;
    for (int off = 32; off > 0; off >>= 1) {
        const float od = __shfl_down(d, off, 64);
        const int   oi = __shfl_down(idx, off, 64);
        if (od < d || (od == d && oi < idx)) { d = od; idx = oi; }
    }
    const int best = __shfl(idx, 0, 64);
    if (k == 0) { ids[b] = best; atomicAdd(&counts[best], 1); }
#pragma unroll
    for (int j = 0; j < 4; ++j)
        atomicAdd(&sums[(size_t)best * LSTM_H + k * 4 + j], row[k * 4 + j]);
}

__global__ __launch_bounds__(256) void centroid_final(
    const float* __restrict__ sums, const int* __restrict__ counts,
    const float* __restrict__ clusters, float* __restrict__ upd)
{
    const int k = blockIdx.x;
    const int h = threadIdx.x;
    const int c = counts[k];
    upd[(size_t)k * LSTM_H + h] = (c > 0)
        ? sums[(size_t)k * LSTM_H + h] / (float)c
        : clusters[(size_t)k * LSTM_H + h];
}

__global__ __launch_bounds__(256) void loss_kernel(
    const float* __restrict__ lat, const int* __restrict__ ids,
    const float* __restrict__ upd, float* __restrict__ out_loss)
{
    float p = 0.f;
    const int total = LSTM_B * LSTM_H;
    for (int idx = blockIdx.x * blockDim.x + threadIdx.x; idx < total;
         idx += gridDim.x * blockDim.x) {
        const int b = idx >> 8;
        const float d = lat[idx] - upd[(size_t)ids[b] * LSTM_H + (idx & 255)];
        p += d * d;
    }
    for (int off = 32; off > 0; off >>= 1) p += __shfl_down(p, off, 64);
    __shared__ float wsum[4];
    const int lane = threadIdx.x & 63, wid = threadIdx.x >> 6;
    if (lane == 0) wsum[wid] = p;
    __syncthreads();
    if (threadIdx.x == 0)
        atomicAdd(out_loss, HALF_BETA * (wsum[0] + wsum[1] + wsum[2] + wsum[3]));
}

// ---------------------------------------------------------------------------
extern "C" void kernel_launch(void* const* d_in, const int* in_sizes, int n_in,
                              void* d_out, int out_size, void* d_ws, size_t ws_size,
                              hipStream_t stream)
{
    const float* X     = (const float*)d_in[0];
    const float* Wih0  = (const float*)d_in[1];
    const float* Whh0  = (const float*)d_in[2];
    const float* bih0  = (const float*)d_in[3];
    const float* bhh0  = (const float*)d_in[4];
    const float* Wih1  = (const float*)d_in[5];
    const float* Whh1  = (const float*)d_in[6];
    const float* bih1  = (const float*)d_in[7];
    const float* bhh1  = (const float*)d_in[8];
    const float* clust = (const float*)d_in[9];

    float* out = (float*)d_out;
    char* base = (char*)d_ws;
    const size_t MB = 1u << 20;
    const size_t KB = 1024;

    u16* Wp0    = (u16*)(base + 0 * MB);              // 640 KB
    u16* Wp1    = (u16*)(base + 1 * MB);              // 1 MB
    u32* h0b0   = (u32*)(base + 2 * MB);              // 1 MB each
    u32* h0b1   = (u32*)(base + 3 * MB);
    u32* h1b0   = (u32*)(base + 4 * MB);
    u32* h1b1   = (u32*)(base + 5 * MB);
    float* sums = (float*)(base + 6 * MB);            // 64 KB
    float* upd  = (float*)(base + 6 * MB + 64 * KB);  // 64 KB
    int* counts = (int*)(base + 6 * MB + 128 * KB);   // 256 B
    int* ids    = (int*)(base + 6 * MB + 132 * KB);   // 8 KB
    u32* cnt0   = (u32*)(base + 6 * MB + 144 * KB);   // 2 KB
    u32* cnt1   = (u32*)(base + 6 * MB + 148 * KB);   // 2 KB

    const size_t BH = (size_t)LSTM_B * LSTM_H;

    hipMemsetAsync(h0b1, 0, MB, stream);   // h0^{-1}
    hipMemsetAsync(h1b1, 0, MB, stream);   // h1^{-1}
    hipMemsetAsync(base + 6 * MB, 0, 152 * KB, stream);
    hipMemsetAsync(out + BH, 0, sizeof(float), stream);

    pack_frag<LSTM_HIN><<<320, 256, 0, stream>>>(Wih0, Whh0, Wp0);
    pack_frag<LSTM_H>  <<<512, 256, 0, stream>>>(Wih1, Whh1, Wp1);

    hipFuncSetAttribute((const void*)lstm_persist3,
                        hipFuncAttributeMaxDynamicSharedMemorySize, LDS_BYTES);

    float* lat = out;
    void* args[] = {
        (void*)&X, (void*)&Wp0, (void*)&Wp1,
        (void*)&bih0, (void*)&bhh0, (void*)&bih1, (void*)&bhh1,
        (void*)&h0b0, (void*)&h0b1, (void*)&h1b0, (void*)&h1b1,
        (void*)&lat, (void*)&cnt0, (void*)&cnt1
    };
    hipLaunchCooperativeKernel((void*)lstm_persist3, dim3(256), dim3(512),
                               args, LDS_BYTES, stream);

    assign_accum<<<LSTM_B, 64, 0, stream>>>(out, clust, ids, sums, counts);
    centroid_final<<<NCLUST, 256, 0, stream>>>(sums, counts, clust, upd);
    loss_kernel<<<256, 256, 0, stream>>>(out, ids, upd, out + BH);
}

// Round 9
// 2817.132 us; speedup vs baseline: 5.5090x; 1.7947x over previous
//
#include <hip/hip_runtime.h>
#include <hip/hip_bf16.h>
#include <math.h>

typedef unsigned short u16;
typedef unsigned int u32;
typedef __attribute__((ext_vector_type(8))) __bf16 bf16x8;
typedef __attribute__((ext_vector_type(4))) float f32x4;

#define LSTM_L 200
#define LSTM_B 2048
#define LSTM_HIN 64
#define LSTM_H 256
#define NCLUST 64
#define HALF_BETA 0.05f
#define LDS_BYTES 131072

__device__ __forceinline__ void gload_lds16(const void* g, void* l) {
    __builtin_amdgcn_global_load_lds(
        (__attribute__((address_space(1))) const void*)g,
        (__attribute__((address_space(3))) void*)l, 16, 0, 0);
}

__device__ __forceinline__ float fast_sigmoid(float x) {
    return __builtin_amdgcn_rcpf(1.f + __expf(-x));
}
__device__ __forceinline__ float fast_tanh(float x) {
    return 2.f * __builtin_amdgcn_rcpf(1.f + __expf(-2.f * x)) - 1.f;
}

// ---------------------------------------------------------------------------
// Weight pack into per-(nb,wn) fragment order (round-4 layout):
// i = ((((nb*4+wn)*NCH + ch)*2 + nf)*64 + lane)*8 + e
// j = (2*nf + (l15&1))*256 + nb*32 + wn*8 + (l15>>1); k = ch*32 + (lane>>4)*8 + e
// ---------------------------------------------------------------------------
template<int KIN>
__global__ __launch_bounds__(256) void pack_frag(
    const float* __restrict__ Wih, const float* __restrict__ Whh,
    u16* __restrict__ Wp)
{
    constexpr int NCH = (KIN + LSTM_H) / 32;
    const int total = 1024 * (KIN + LSTM_H);
    for (int i = blockIdx.x * 256 + threadIdx.x; i < total; i += gridDim.x * 256) {
        const int e = i & 7;
        int t = i >> 3;
        const int lane = t & 63; t >>= 6;
        const int nf = t & 1;    t >>= 1;
        const int ch = t % NCH;  t /= NCH;
        const int wn = t & 3;
        const int nb = t >> 2;
        const int l15 = lane & 15;
        const int j = (2 * nf + (l15 & 1)) * 256 + nb * 32 + wn * 8 + (l15 >> 1);
        const int k = ch * 32 + ((lane >> 4) << 3) + e;
        const float v = (k < KIN) ? Wih[(size_t)j * KIN + k]
                                  : Whh[(size_t)j * LSTM_H + (k - KIN)];
        Wp[i] = __builtin_bit_cast(u16, (__bf16)v);
    }
}

// ---------------------------------------------------------------------------
// One layer step. Block = 128 rows x 128 gatecols; 8 waves (2m x 4n);
// wave = 64 rows x 32 cols (4 m-frags x 2 n-frags of 16x16x32 bf16 MFMA).
// B (weights) in VGPRs, loaded once from frag-packed Wp. A staged to LDS once
// (XOR-swizzled), then a barrier-free fully-unrolled K loop.
// Col mapping: lane l15 -> hcol = nb*32 + wn*8 + (l15>>1); nf0 gates {i,f},
// nf1 gates {g,o}, gate parity = l15&1 -> pointwise via 2x shfl_xor(1).
// ---------------------------------------------------------------------------
template<int KIN>
__device__ __forceinline__ void run_layer(
    const float* __restrict__ xf32,     // L0: X slice (f32), else nullptr
    const u16* __restrict__ hbelow,     // L1: h0 current; L0: unused
    const u16* __restrict__ hself,      // recurrent hidden (bf16)
    const u16* __restrict__ Wp,
    const float* __restrict__ bih, const float* __restrict__ bhh,
    u16* __restrict__ hout, float* __restrict__ latout,
    float* __restrict__ cst,
    int blk, char* smem, int tid)
{
    constexpr int NCH = (KIN + LSTM_H) / 32;
    constexpr bool IS_L0 = (KIN == 64);
    const int lane = tid & 63;
    const int w = tid >> 6;
    const int wm = w >> 2;            // 0..1
    const int wn = w & 3;             // 0..3
    const int l15 = lane & 15;
    const int q = lane >> 4;          // 0..3
    const int mb = blk >> 3;
    const int nb = blk & 7;
    const int b0 = mb * 128;

    // ---- B into registers (frag-packed, contiguous 16B loads) ----
    bf16x8 Breg[NCH][2];
    {
        const u16* wp = Wp + (size_t)((nb * 4 + wn) * NCH) * 1024 + lane * 8;
#pragma unroll
        for (int ch = 0; ch < NCH; ++ch)
#pragma unroll
            for (int nf = 0; nf < 2; ++nf)
                Breg[ch][nf] = *(const bf16x8*)(wp + (ch * 2 + nf) * 512);
    }

    // ---- c-state preload ----
    const int hcol = nb * 32 + wn * 8 + (l15 >> 1);
    const int rowA = wm * 64;
    float cp[4][4];
#pragma unroll
    for (int mf = 0; mf < 4; ++mf)
#pragma unroll
        for (int r = 0; r < 4; ++r)
            cp[mf][r] = cst[(size_t)(b0 + rowA + mf * 16 + q * 4 + r) * 256 + hcol];

    // ---- bias ----
    const int gpar = l15 & 1;
    const float b0a = bih[gpar * 256 + hcol] + bhh[gpar * 256 + hcol];
    const float b1a = bih[(2 + gpar) * 256 + hcol] + bhh[(2 + gpar) * 256 + hcol];

    // ---- stage A into LDS (swizzled source, linear dest) ----
    if (IS_L0) {
        // H region: [128 rows][512 B] at 0, via global_load_lds
#pragma unroll
        for (int i = 0; i < 8; ++i) {
            const int slot = i * 512 + tid;
            const int row = slot >> 5;
            const int so = (slot & 31) * 16;
            const int koff = so ^ ((row & 7) << 4);
            gload_lds16((const char*)hself + (size_t)(b0 + row) * 512 + koff,
                        smem + slot * 16);
        }
        // X region: [128 rows][128 B] at 65536, reg-convert f32->bf16
#pragma unroll
        for (int p = 0; p < 2; ++p) {
            const int slot = p * 512 + tid;
            const int row = slot >> 3;
            const int so = (slot & 7) * 16;
            const int koff = so ^ ((row & 7) << 4);
            const float* s = xf32 + (size_t)(b0 + row) * 64 + (koff >> 1);
            const float4 v0 = *(const float4*)s;
            const float4 v1 = *(const float4*)(s + 4);
            bf16x8 pk;
            pk[0] = (__bf16)v0.x; pk[1] = (__bf16)v0.y;
            pk[2] = (__bf16)v0.z; pk[3] = (__bf16)v0.w;
            pk[4] = (__bf16)v1.x; pk[5] = (__bf16)v1.y;
            pk[6] = (__bf16)v1.z; pk[7] = (__bf16)v1.w;
            *(bf16x8*)(smem + 65536 + slot * 16) = pk;
        }
    } else {
        // single region: [128 rows][1024 B]: first 512 = hbelow, rest = hself
#pragma unroll
        for (int i = 0; i < 16; ++i) {
            const int slot = i * 512 + tid;
            const int row = slot >> 6;
            const int so = (slot & 63) * 16;
            const int koff = so ^ ((row & 7) << 4);
            const char* src = (koff < 512)
                ? (const char*)hbelow + (size_t)(b0 + row) * 512 + koff
                : (const char*)hself + (size_t)(b0 + row) * 512 + (koff - 512);
            gload_lds16(src, smem + slot * 16);
        }
    }
    __syncthreads();

    // ---- barrier-free K loop ----
    f32x4 acc[4][2];
#pragma unroll
    for (int mf = 0; mf < 4; ++mf)
#pragma unroll
        for (int nf = 0; nf < 2; ++nf) acc[mf][nf] = f32x4{0.f, 0.f, 0.f, 0.f};

    const int qoff = q * 16;
    const int swzl = (l15 & 7) << 4;
#pragma unroll
    for (int ch = 0; ch < NCH; ++ch) {
        bf16x8 af[4];
#pragma unroll
        for (int mf = 0; mf < 4; ++mf) {
            const int row = rowA + mf * 16 + l15;
            const char* ap;
            if (IS_L0) {
                if (ch < 2)
                    ap = smem + 65536 + row * 128 + ((ch * 64 + qoff) ^ swzl);
                else
                    ap = smem + row * 512 + (((ch - 2) * 64 + qoff) ^ swzl);
            } else {
                ap = smem + row * 1024 + ((ch * 64 + qoff) ^ swzl);
            }
            af[mf] = *(const bf16x8*)ap;
        }
#pragma unroll
        for (int mf = 0; mf < 4; ++mf)
#pragma unroll
            for (int nf = 0; nf < 2; ++nf)
                acc[mf][nf] = __builtin_amdgcn_mfma_f32_16x16x32_bf16(
                    af[mf], Breg[ch][nf], acc[mf][nf], 0, 0, 0);
    }

    // ---- pointwise epilogue: gather 4 gates via 2 shfl_xor(1) ----
#pragma unroll
    for (int mf = 0; mf < 4; ++mf) {
#pragma unroll
        for (int r = 0; r < 4; ++r) {
            const float a0 = acc[mf][0][r] + b0a;
            const float a1 = acc[mf][1][r] + b1a;
            const float p0 = __shfl_xor(a0, 1);
            const float p1 = __shfl_xor(a1, 1);
            const float gi = gpar ? p0 : a0;
            const float gf = gpar ? a0 : p0;
            const float gg = gpar ? p1 : a1;
            const float go = gpar ? a1 : p1;
            const float cn = fast_sigmoid(gf) * cp[mf][r]
                           + fast_sigmoid(gi) * fast_tanh(gg);
            const float hv = fast_sigmoid(go) * fast_tanh(cn);
            const size_t oidx =
                (size_t)(b0 + rowA + mf * 16 + q * 4 + r) * 256 + hcol;
            if (gpar) {
                cst[oidx] = cn;                       // odd lane: c-state
            } else if (latout) {
                latout[oidx] = hv;                    // final slot: f32 latent
            } else {
                hout[oidx] = __builtin_bit_cast(u16, (__bf16)hv);
            }
        }
    }
}

// Slot s: blocks 0..127 -> layer0 step s; 128..255 -> layer1 step s-1.
// LDS (128KB) already caps at 1 block/CU; launch_bounds(512,1) frees the
// register file (L1 needs ~190 VGPR live: Breg[16][2]=128 + acc + frags).
__global__ __launch_bounds__(512, 1) void lstm_slot(
    const float* __restrict__ xt,
    const u16* __restrict__ h0c, u16* __restrict__ h0n, float* __restrict__ c0,
    const u16* __restrict__ Wp0,
    const float* __restrict__ bih0, const float* __restrict__ bhh0,
    const u16* __restrict__ h1c, u16* __restrict__ h1n, float* __restrict__ c1,
    const u16* __restrict__ Wp1,
    const float* __restrict__ bih1, const float* __restrict__ bhh1,
    float* __restrict__ latout, int do0, int do1)
{
    extern __shared__ char smem[];
    const int tid = threadIdx.x;
    if (blockIdx.x < 128) {
        if (do0)
            run_layer<LSTM_HIN>(xt, nullptr, h0c, Wp0, bih0, bhh0,
                                h0n, nullptr, c0, blockIdx.x, smem, tid);
    } else {
        if (do1)
            run_layer<LSTM_H>(nullptr, h0c, h1c, Wp1, bih1, bhh1,
                              h1n, latout, c1, blockIdx.x - 128, smem, tid);
    }
}

// ---------------------------------------------------------------------------
// K-means tail: assign + atomic accumulation, finalize, loss (round-8 proven)
// ---------------------------------------------------------------------------
__global__ __launch_bounds__(64) void assign_accum(
    const float* __restrict__ lat, const float* __restrict__ clusters,
    int* __restrict__ ids, float* __restrict__ sums, int* __restrict__ counts)
{
    __shared__ float row[LSTM_H];
    const int b = blockIdx.x;
    const int k = threadIdx.x;
    for (int i = k; i < LSTM_H; i += 64) row[i] = lat[(size_t)b * LSTM_H + i];
    __syncthreads();
    const float* ck = clusters + (size_t)k * LSTM_H;
    float d = 0.f;
#pragma unroll 8
    for (int i = 0; i < LSTM_H; ++i) { const float t = row[i] - ck[i]; d += t * t; }
    int idx = k;
    for (int off = 32; off > 0; off >>= 1) {
        const float od = __shfl_down(d, off, 64);
        const int   oi = __shfl_down(idx, off, 64);
        if (od < d || (od == d && oi < idx)) { d = od; idx = oi; }
    }
    const int best = __shfl(idx, 0, 64);
    if (k == 0) { ids[b] = best; atomicAdd(&counts[best], 1); }
#pragma unroll
    for (int j = 0; j < 4; ++j)
        atomicAdd(&sums[(size_t)best * LSTM_H + k * 4 + j], row[k * 4 + j]);
}

__global__ __launch_bounds__(256) void centroid_final(
    const float* __restrict__ sums, const int* __restrict__ counts,
    const float* __restrict__ clusters, float* __restrict__ upd)
{
    const int k = blockIdx.x;
    const int h = threadIdx.x;
    const int c = counts[k];
    upd[(size_t)k * LSTM_H + h] = (c > 0)
        ? sums[(size_t)k * LSTM_H + h] / (float)c
        : clusters[(size_t)k * LSTM_H + h];
}

__global__ __launch_bounds__(256) void loss_kernel(
    const float* __restrict__ lat, const int* __restrict__ ids,
    const float* __restrict__ upd, float* __restrict__ out_loss)
{
    float p = 0.f;
    const int total = LSTM_B * LSTM_H;
    for (int idx = blockIdx.x * blockDim.x + threadIdx.x; idx < total;
         idx += gridDim.x * blockDim.x) {
        const int b = idx >> 8;
        const float d = lat[idx] - upd[(size_t)ids[b] * LSTM_H + (idx & 255)];
        p += d * d;
    }
    for (int off = 32; off > 0; off >>= 1) p += __shfl_down(p, off, 64);
    __shared__ float wsum[4];
    const int lane = threadIdx.x & 63, wid = threadIdx.x >> 6;
    if (lane == 0) wsum[wid] = p;
    __syncthreads();
    if (threadIdx.x == 0)
        atomicAdd(out_loss, HALF_BETA * (wsum[0] + wsum[1] + wsum[2] + wsum[3]));
}

// ---------------------------------------------------------------------------
extern "C" void kernel_launch(void* const* d_in, const int* in_sizes, int n_in,
                              void* d_out, int out_size, void* d_ws, size_t ws_size,
                              hipStream_t stream)
{
    const float* X     = (const float*)d_in[0];
    const float* Wih0  = (const float*)d_in[1];
    const float* Whh0  = (const float*)d_in[2];
    const float* bih0  = (const float*)d_in[3];
    const float* bhh0  = (const float*)d_in[4];
    const float* Wih1  = (const float*)d_in[5];
    const float* Whh1  = (const float*)d_in[6];
    const float* bih1  = (const float*)d_in[7];
    const float* bhh1  = (const float*)d_in[8];
    const float* clust = (const float*)d_in[9];

    float* out = (float*)d_out;
    char* base = (char*)d_ws;
    const size_t MB = 1u << 20;
    const size_t KB = 1024;

    u16* Wp0    = (u16*)(base + 0 * MB);              // 640 KB
    u16* Wp1    = (u16*)(base + 1 * MB);              // 1 MB
    u16* h0a    = (u16*)(base + 2 * MB);              // 1 MB each
    u16* h0b    = (u16*)(base + 3 * MB);
    u16* h1a    = (u16*)(base + 4 * MB);
    u16* h1b    = (u16*)(base + 5 * MB);
    float* c0   = (float*)(base + 6 * MB);            // 2 MB
    float* c1   = (float*)(base + 8 * MB);            // 2 MB
    float* sums = (float*)(base + 10 * MB);           // 64 KB
    float* upd  = (float*)(base + 10 * MB + 64 * KB); // 64 KB
    int* counts = (int*)(base + 10 * MB + 128 * KB);  // 256 B
    int* ids    = (int*)(base + 10 * MB + 132 * KB);  // 8 KB

    const size_t BH = (size_t)LSTM_B * LSTM_H;

    hipMemsetAsync(h0a, 0, MB, stream);
    hipMemsetAsync(h1a, 0, MB, stream);
    hipMemsetAsync(c0, 0, 4 * MB, stream);            // c0+c1 contiguous
    hipMemsetAsync(base + 10 * MB, 0, 144 * KB, stream);
    hipMemsetAsync(out + BH, 0, sizeof(float), stream);

    pack_frag<LSTM_HIN><<<320, 256, 0, stream>>>(Wih0, Whh0, Wp0);
    pack_frag<LSTM_H>  <<<512, 256, 0, stream>>>(Wih1, Whh1, Wp1);

    hipFuncSetAttribute((const void*)lstm_slot,
                        hipFuncAttributeMaxDynamicSharedMemorySize, LDS_BYTES);

    u16* h0c = h0a; u16* h0n = h0b;
    u16* h1c = h1a; u16* h1n = h1b;
    for (int s = 0; s <= LSTM_L; ++s) {
        const int do0 = (s < LSTM_L) ? 1 : 0;
        const int do1 = (s > 0) ? 1 : 0;
        const float* xt = do0 ? X + (size_t)s * LSTM_B * LSTM_HIN : nullptr;
        float* lat = (s == LSTM_L) ? out : nullptr;
        lstm_slot<<<256, 512, LDS_BYTES, stream>>>(
            xt, h0c, h0n, c0, Wp0, bih0, bhh0,
            h1c, h1n, c1, Wp1, bih1, bhh1, lat, do0, do1);
        if (do0) { u16* t = h0c; h0c = h0n; h0n = t; }
        if (do1) { u16* t = h1c; h1c = h1n; h1n = t; }
    }

    assign_accum<<<LSTM_B, 64, 0, stream>>>(out, clust, ids, sums, counts);
    centroid_final<<<NCLUST, 256, 0, stream>>>(sums, counts, clust, upd);
    loss_kernel<<<256, 256, 0, stream>>>(out, ids, upd, out + BH);
}

// Round 10
// 2809.973 us; speedup vs baseline: 5.5230x; 1.0025x over previous
//
#include <hip/hip_runtime.h>
#include <hip/hip_bf16.h>
#include <math.h>

typedef unsigned short u16;
typedef unsigned int u32;
typedef __attribute__((ext_vector_type(8))) __bf16 bf16x8;
typedef __attribute__((ext_vector_type(4))) float f32x4;

#define LSTM_L 200
#define LSTM_B 2048
#define LSTM_HIN 64
#define LSTM_H 256
#define NCLUST 64
#define HALF_BETA 0.05f
#define LDS_BYTES 131072

__device__ __forceinline__ void gload_lds16(const void* g, void* l) {
    __builtin_amdgcn_global_load_lds(
        (__attribute__((address_space(1))) const void*)g,
        (__attribute__((address_space(3))) void*)l, 16, 0, 0);
}

__device__ __forceinline__ float fast_sigmoid(float x) {
    return __builtin_amdgcn_rcpf(1.f + __expf(-x));
}
__device__ __forceinline__ float fast_tanh(float x) {
    return 2.f * __builtin_amdgcn_rcpf(1.f + __expf(-2.f * x)) - 1.f;
}

// ---------------------------------------------------------------------------
// Weight pack into per-(nb,wn) fragment order (round-4 layout):
// i = ((((nb*4+wn)*NCH + ch)*2 + nf)*64 + lane)*8 + e
// j = (2*nf + (l15&1))*256 + nb*32 + wn*8 + (l15>>1); k = ch*32 + (lane>>4)*8 + e
// ---------------------------------------------------------------------------
template<int KIN>
__global__ __launch_bounds__(256) void pack_frag(
    const float* __restrict__ Wih, const float* __restrict__ Whh,
    u16* __restrict__ Wp)
{
    constexpr int NCH = (KIN + LSTM_H) / 32;
    const int total = 1024 * (KIN + LSTM_H);
    for (int i = blockIdx.x * 256 + threadIdx.x; i < total; i += gridDim.x * 256) {
        const int e = i & 7;
        int t = i >> 3;
        const int lane = t & 63; t >>= 6;
        const int nf = t & 1;    t >>= 1;
        const int ch = t % NCH;  t /= NCH;
        const int wn = t & 3;
        const int nb = t >> 2;
        const int l15 = lane & 15;
        const int j = (2 * nf + (l15 & 1)) * 256 + nb * 32 + wn * 8 + (l15 >> 1);
        const int k = ch * 32 + ((lane >> 4) << 3) + e;
        const float v = (k < KIN) ? Wih[(size_t)j * KIN + k]
                                  : Whh[(size_t)j * LSTM_H + (k - KIN)];
        Wp[i] = __builtin_bit_cast(u16, (__bf16)v);
    }
}

// ---------------------------------------------------------------------------
// One layer step. Block = 128 rows x 128 gatecols; 8 waves (2m x 4n);
// wave = 64 rows x 32 cols (4 m-frags x 2 n-frags of 16x16x32 bf16 MFMA).
// B (weights) in VGPRs, loaded once from frag-packed Wp. A staged to LDS once
// (XOR-swizzled), then a barrier-free fully-unrolled K loop.
// ---------------------------------------------------------------------------
template<int KIN>
__device__ __forceinline__ void run_layer(
    const float* __restrict__ xf32,     // L0: X slice (f32), else nullptr
    const u16* __restrict__ hbelow,     // L1: h0 current; L0: unused
    const u16* __restrict__ hself,      // recurrent hidden (bf16)
    const u16* __restrict__ Wp,
    const float* __restrict__ bih, const float* __restrict__ bhh,
    u16* __restrict__ hout, float* __restrict__ latout,
    float* __restrict__ cst,
    int blk, char* smem, int tid)
{
    constexpr int NCH = (KIN + LSTM_H) / 32;
    constexpr bool IS_L0 = (KIN == 64);
    const int lane = tid & 63;
    const int w = tid >> 6;
    const int wm = w >> 2;            // 0..1
    const int wn = w & 3;             // 0..3
    const int l15 = lane & 15;
    const int q = lane >> 4;          // 0..3
    const int mb = blk >> 3;
    const int nb = blk & 7;
    const int b0 = mb * 128;

    // ---- B into registers (frag-packed, contiguous 16B loads) ----
    bf16x8 Breg[NCH][2];
    {
        const u16* wp = Wp + (size_t)((nb * 4 + wn) * NCH) * 1024 + lane * 8;
#pragma unroll
        for (int ch = 0; ch < NCH; ++ch)
#pragma unroll
            for (int nf = 0; nf < 2; ++nf)
                Breg[ch][nf] = *(const bf16x8*)(wp + (ch * 2 + nf) * 512);
    }

    // ---- c-state preload ----
    const int hcol = nb * 32 + wn * 8 + (l15 >> 1);
    const int rowA = wm * 64;
    float cp[4][4];
#pragma unroll
    for (int mf = 0; mf < 4; ++mf)
#pragma unroll
        for (int r = 0; r < 4; ++r)
            cp[mf][r] = cst[(size_t)(b0 + rowA + mf * 16 + q * 4 + r) * 256 + hcol];

    // ---- bias ----
    const int gpar = l15 & 1;
    const float b0a = bih[gpar * 256 + hcol] + bhh[gpar * 256 + hcol];
    const float b1a = bih[(2 + gpar) * 256 + hcol] + bhh[(2 + gpar) * 256 + hcol];

    // ---- stage A into LDS (swizzled source, linear dest) ----
    if (IS_L0) {
        // H region: [128 rows][512 B] at 0, via global_load_lds
#pragma unroll
        for (int i = 0; i < 8; ++i) {
            const int slot = i * 512 + tid;
            const int row = slot >> 5;
            const int so = (slot & 31) * 16;
            const int koff = so ^ ((row & 7) << 4);
            gload_lds16((const char*)hself + (size_t)(b0 + row) * 512 + koff,
                        smem + slot * 16);
        }
        // X region: [128 rows][128 B] at 65536, reg-convert f32->bf16
#pragma unroll
        for (int p = 0; p < 2; ++p) {
            const int slot = p * 512 + tid;
            const int row = slot >> 3;
            const int so = (slot & 7) * 16;
            const int koff = so ^ ((row & 7) << 4);
            const float* s = xf32 + (size_t)(b0 + row) * 64 + (koff >> 1);
            const float4 v0 = *(const float4*)s;
            const float4 v1 = *(const float4*)(s + 4);
            bf16x8 pk;
            pk[0] = (__bf16)v0.x; pk[1] = (__bf16)v0.y;
            pk[2] = (__bf16)v0.z; pk[3] = (__bf16)v0.w;
            pk[4] = (__bf16)v1.x; pk[5] = (__bf16)v1.y;
            pk[6] = (__bf16)v1.z; pk[7] = (__bf16)v1.w;
            *(bf16x8*)(smem + 65536 + slot * 16) = pk;
        }
    } else {
        // single region: [128 rows][1024 B]: first 512 = hbelow, rest = hself
#pragma unroll
        for (int i = 0; i < 16; ++i) {
            const int slot = i * 512 + tid;
            const int row = slot >> 6;
            const int so = (slot & 63) * 16;
            const int koff = so ^ ((row & 7) << 4);
            const char* src = (koff < 512)
                ? (const char*)hbelow + (size_t)(b0 + row) * 512 + koff
                : (const char*)hself + (size_t)(b0 + row) * 512 + (koff - 512);
            gload_lds16(src, smem + slot * 16);
        }
    }
    __syncthreads();

    // ---- barrier-free K loop ----
    f32x4 acc[4][2];
#pragma unroll
    for (int mf = 0; mf < 4; ++mf)
#pragma unroll
        for (int nf = 0; nf < 2; ++nf) acc[mf][nf] = f32x4{0.f, 0.f, 0.f, 0.f};

    const int qoff = q * 16;
    const int swzl = (l15 & 7) << 4;
#pragma unroll
    for (int ch = 0; ch < NCH; ++ch) {
        bf16x8 af[4];
#pragma unroll
        for (int mf = 0; mf < 4; ++mf) {
            const int row = rowA + mf * 16 + l15;
            const char* ap;
            if (IS_L0) {
                if (ch < 2)
                    ap = smem + 65536 + row * 128 + ((ch * 64 + qoff) ^ swzl);
                else
                    ap = smem + row * 512 + (((ch - 2) * 64 + qoff) ^ swzl);
            } else {
                ap = smem + row * 1024 + ((ch * 64 + qoff) ^ swzl);
            }
            af[mf] = *(const bf16x8*)ap;
        }
#pragma unroll
        for (int mf = 0; mf < 4; ++mf)
#pragma unroll
            for (int nf = 0; nf < 2; ++nf)
                acc[mf][nf] = __builtin_amdgcn_mfma_f32_16x16x32_bf16(
                    af[mf], Breg[ch][nf], acc[mf][nf], 0, 0, 0);
    }

    // ---- pointwise epilogue: gather 4 gates via 2 shfl_xor(1) ----
#pragma unroll
    for (int mf = 0; mf < 4; ++mf) {
#pragma unroll
        for (int r = 0; r < 4; ++r) {
            const float a0 = acc[mf][0][r] + b0a;
            const float a1 = acc[mf][1][r] + b1a;
            const float p0 = __shfl_xor(a0, 1);
            const float p1 = __shfl_xor(a1, 1);
            const float gi = gpar ? p0 : a0;
            const float gf = gpar ? a0 : p0;
            const float gg = gpar ? p1 : a1;
            const float go = gpar ? a1 : p1;
            const float cn = fast_sigmoid(gf) * cp[mf][r]
                           + fast_sigmoid(gi) * fast_tanh(gg);
            const float hv = fast_sigmoid(go) * fast_tanh(cn);
            const size_t oidx =
                (size_t)(b0 + rowA + mf * 16 + q * 4 + r) * 256 + hcol;
            if (gpar) {
                cst[oidx] = cn;                       // odd lane: c-state
            } else if (latout) {
                latout[oidx] = hv;                    // final slot: f32 latent
            } else {
                hout[oidx] = __builtin_bit_cast(u16, (__bf16)hv);
            }
        }
    }
}

// Slot s: blocks 0..127 -> layer0 step s; 128..255 -> layer1 step s-1.
// LDS (128KB) caps at 1 block/CU; (512,1) frees the register file.
__global__ __launch_bounds__(512, 1) void lstm_slot(
    const float* __restrict__ xt,
    const u16* __restrict__ h0c, u16* __restrict__ h0n, float* __restrict__ c0,
    const u16* __restrict__ Wp0,
    const float* __restrict__ bih0, const float* __restrict__ bhh0,
    const u16* __restrict__ h1c, u16* __restrict__ h1n, float* __restrict__ c1,
    const u16* __restrict__ Wp1,
    const float* __restrict__ bih1, const float* __restrict__ bhh1,
    float* __restrict__ latout, int do0, int do1)
{
    extern __shared__ char smem[];
    const int tid = threadIdx.x;
    if (blockIdx.x < 128) {
        if (do0)
            run_layer<LSTM_HIN>(xt, nullptr, h0c, Wp0, bih0, bhh0,
                                h0n, nullptr, c0, blockIdx.x, smem, tid);
    } else {
        if (do1)
            run_layer<LSTM_H>(nullptr, h0c, h1c, Wp1, bih1, bhh1,
                              h1n, latout, c1, blockIdx.x - 128, smem, tid);
    }
}

// ---------------------------------------------------------------------------
// K-means tail.
// transpose_clusters: clT4[j][k] = clusters[k][4j..4j+3]  (j=0..63, k=0..63)
// -> assign reads are consecutive 16B across the 64 lanes (fully coalesced).
// ---------------------------------------------------------------------------
__global__ __launch_bounds__(256) void transpose_clusters(
    const float* __restrict__ cl, float4* __restrict__ clT4)
{
    const int t = blockIdx.x * 256 + threadIdx.x;   // 4096 float4 elements
    const int j = t & 63;
    const int k = t >> 6;
    const float4 v = *(const float4*)&cl[(size_t)k * 256 + j * 4];
    clT4[(size_t)j * 64 + k] = v;
}

__global__ __launch_bounds__(64) void assign_accum(
    const float* __restrict__ lat, const float4* __restrict__ clT4,
    int* __restrict__ ids, float* __restrict__ sums, int* __restrict__ counts)
{
    __shared__ float row[LSTM_H];
    const int b = blockIdx.x;
    const int k = threadIdx.x;   // lane = cluster
    for (int i = k; i < LSTM_H; i += 64) row[i] = lat[(size_t)b * LSTM_H + i];
    __syncthreads();
    float d = 0.f;
#pragma unroll 8
    for (int j = 0; j < 64; ++j) {
        const float4 c4 = clT4[(size_t)j * 64 + k];     // coalesced: 16B x 64 lanes
        const float4 x4 = *(const float4*)&row[j * 4];  // LDS broadcast
        const float t0 = x4.x - c4.x;
        const float t1 = x4.y - c4.y;
        const float t2 = x4.z - c4.z;
        const float t3 = x4.w - c4.w;
        d += t0 * t0 + t1 * t1 + t2 * t2 + t3 * t3;
    }
    int idx = k;
    for (int off = 32; off > 0; off >>= 1) {
        const float od = __shfl_down(d, off, 64);
        const int   oi = __shfl_down(idx, off, 64);
        if (od < d || (od == d && oi < idx)) { d = od; idx = oi; }
    }
    const int best = __shfl(idx, 0, 64);
    if (k == 0) { ids[b] = best; atomicAdd(&counts[best], 1); }
#pragma unroll
    for (int j = 0; j < 4; ++j)
        atomicAdd(&sums[(size_t)best * LSTM_H + k * 4 + j], row[k * 4 + j]);
}

__global__ __launch_bounds__(256) void centroid_final(
    const float* __restrict__ sums, const int* __restrict__ counts,
    const float* __restrict__ clusters, float* __restrict__ upd)
{
    const int k = blockIdx.x;
    const int h = threadIdx.x;
    const int c = counts[k];
    upd[(size_t)k * LSTM_H + h] = (c > 0)
        ? sums[(size_t)k * LSTM_H + h] / (float)c
        : clusters[(size_t)k * LSTM_H + h];
}

__global__ __launch_bounds__(256) void loss_kernel(
    const float* __restrict__ lat, const int* __restrict__ ids,
    const float* __restrict__ upd, float* __restrict__ out_loss)
{
    float p = 0.f;
    const int total = LSTM_B * LSTM_H;
    for (int idx = blockIdx.x * blockDim.x + threadIdx.x; idx < total;
         idx += gridDim.x * blockDim.x) {
        const int b = idx >> 8;
        const float d = lat[idx] - upd[(size_t)ids[b] * LSTM_H + (idx & 255)];
        p += d * d;
    }
    for (int off = 32; off > 0; off >>= 1) p += __shfl_down(p, off, 64);
    __shared__ float wsum[4];
    const int lane = threadIdx.x & 63, wid = threadIdx.x >> 6;
    if (lane == 0) wsum[wid] = p;
    __syncthreads();
    if (threadIdx.x == 0)
        atomicAdd(out_loss, HALF_BETA * (wsum[0] + wsum[1] + wsum[2] + wsum[3]));
}

// ---------------------------------------------------------------------------
extern "C" void kernel_launch(void* const* d_in, const int* in_sizes, int n_in,
                              void* d_out, int out_size, void* d_ws, size_t ws_size,
                              hipStream_t stream)
{
    const float* X     = (const float*)d_in[0];
    const float* Wih0  = (const float*)d_in[1];
    const float* Whh0  = (const float*)d_in[2];
    const float* bih0  = (const float*)d_in[3];
    const float* bhh0  = (const float*)d_in[4];
    const float* Wih1  = (const float*)d_in[5];
    const float* Whh1  = (const float*)d_in[6];
    const float* bih1  = (const float*)d_in[7];
    const float* bhh1  = (const float*)d_in[8];
    const float* clust = (const float*)d_in[9];

    float* out = (float*)d_out;
    char* base = (char*)d_ws;
    const size_t MB = 1u << 20;
    const size_t KB = 1024;

    u16* Wp0    = (u16*)(base + 0 * MB);              // 640 KB
    u16* Wp1    = (u16*)(base + 1 * MB);              // 1 MB
    u16* h0a    = (u16*)(base + 2 * MB);              // 1 MB each
    u16* h0b    = (u16*)(base + 3 * MB);
    u16* h1a    = (u16*)(base + 4 * MB);
    u16* h1b    = (u16*)(base + 5 * MB);
    float* c0   = (float*)(base + 6 * MB);            // 2 MB
    float* c1   = (float*)(base + 8 * MB);            // 2 MB
    float* sums = (float*)(base + 10 * MB);           // 64 KB
    float* upd  = (float*)(base + 10 * MB + 64 * KB); // 64 KB
    int* counts = (int*)(base + 10 * MB + 128 * KB);  // 256 B
    int* ids    = (int*)(base + 10 * MB + 132 * KB);  // 8 KB
    float4* clT4 = (float4*)(base + 10 * MB + 144 * KB); // 64 KB

    const size_t BH = (size_t)LSTM_B * LSTM_H;

    hipMemsetAsync(h0a, 0, MB, stream);
    hipMemsetAsync(h1a, 0, MB, stream);
    hipMemsetAsync(c0, 0, 4 * MB, stream);            // c0+c1 contiguous
    hipMemsetAsync(base + 10 * MB, 0, 144 * KB, stream);
    hipMemsetAsync(out + BH, 0, sizeof(float), stream);

    pack_frag<LSTM_HIN><<<320, 256, 0, stream>>>(Wih0, Whh0, Wp0);
    pack_frag<LSTM_H>  <<<512, 256, 0, stream>>>(Wih1, Whh1, Wp1);
    transpose_clusters<<<16, 256, 0, stream>>>(clust, clT4);

    hipFuncSetAttribute((const void*)lstm_slot,
                        hipFuncAttributeMaxDynamicSharedMemorySize, LDS_BYTES);

    u16* h0c = h0a; u16* h0n = h0b;
    u16* h1c = h1a; u16* h1n = h1b;
    for (int s = 0; s <= LSTM_L; ++s) {
        const int do0 = (s < LSTM_L) ? 1 : 0;
        const int do1 = (s > 0) ? 1 : 0;
        const float* xt = do0 ? X + (size_t)s * LSTM_B * LSTM_HIN : nullptr;
        float* lat = (s == LSTM_L) ? out : nullptr;
        lstm_slot<<<256, 512, LDS_BYTES, stream>>>(
            xt, h0c, h0n, c0, Wp0, bih0, bhh0,
            h1c, h1n, c1, Wp1, bih1, bhh1, lat, do0, do1);
        if (do0) { u16* t = h0c; h0c = h0n; h0n = t; }
        if (do1) { u16* t = h1c; h1c = h1n; h1n = t; }
    }

    assign_accum<<<LSTM_B, 64, 0, stream>>>(out, clT4, ids, sums, counts);
    centroid_final<<<NCLUST, 256, 0, stream>>>(sums, counts, clust, upd);
    loss_kernel<<<256, 256, 0, stream>>>(out, ids, upd, out + BH);
}

// Round 13
// 2655.177 us; speedup vs baseline: 5.8450x; 1.0583x over previous
//
#include <hip/hip_runtime.h>
#include <hip/hip_bf16.h>
#include <math.h>

typedef unsigned short u16;
typedef unsigned int u32;
typedef __attribute__((ext_vector_type(8))) __bf16 bf16x8;
typedef __attribute__((ext_vector_type(4))) float f32x4;

#define LSTM_L 200
#define LSTM_B 2048
#define LSTM_HIN 64
#define LSTM_H 256
#define NCLUST 64
#define HALF_BETA 0.05f
#define LDS_BYTES 131072
#define ASSIGN_LDS 135424   // clT 64K + psum 64K + rowbuf 4K + pcnt 256
#define ASSIGN_BLOCKS 32

__device__ __forceinline__ void gload_lds16(const void* g, void* l) {
    __builtin_amdgcn_global_load_lds(
        (__attribute__((address_space(1))) const void*)g,
        (__attribute__((address_space(3))) void*)l, 16, 0, 0);
}

__device__ __forceinline__ float fast_sigmoid(float x) {
    return __builtin_amdgcn_rcpf(1.f + __expf(-x));
}
__device__ __forceinline__ float fast_tanh(float x) {
    return 2.f * __builtin_amdgcn_rcpf(1.f + __expf(-2.f * x)) - 1.f;
}
// Write-through store (agent scope, relaxed): leaves no dirty L2 line behind,
// so the inter-kernel release flush has nothing to write back. Proven to
// reach the coherence point in round 8's fence-free protocol.
__device__ __forceinline__ void wt_store(u32* p, u32 v) {
    __hip_atomic_store(p, v, __ATOMIC_RELAXED, __HIP_MEMORY_SCOPE_AGENT);
}

// ---------------------------------------------------------------------------
// Weight pack into per-(nb,wn) fragment order (round-4 layout):
// i = ((((nb*4+wn)*NCH + ch)*2 + nf)*64 + lane)*8 + e
// j = (2*nf + (l15&1))*256 + nb*32 + wn*8 + (l15>>1); k = ch*32 + (lane>>4)*8 + e
// ---------------------------------------------------------------------------
template<int KIN>
__global__ __launch_bounds__(256) void pack_frag(
    const float* __restrict__ Wih, const float* __restrict__ Whh,
    u16* __restrict__ Wp)
{
    constexpr int NCH = (KIN + LSTM_H) / 32;
    const int total = 1024 * (KIN + LSTM_H);
    for (int i = blockIdx.x * 256 + threadIdx.x; i < total; i += gridDim.x * 256) {
        const int e = i & 7;
        int t = i >> 3;
        const int lane = t & 63; t >>= 6;
        const int nf = t & 1;    t >>= 1;
        const int ch = t % NCH;  t /= NCH;
        const int wn = t & 3;
        const int nb = t >> 2;
        const int l15 = lane & 15;
        const int j = (2 * nf + (l15 & 1)) * 256 + nb * 32 + wn * 8 + (l15 >> 1);
        const int k = ch * 32 + ((lane >> 4) << 3) + e;
        const float v = (k < KIN) ? Wih[(size_t)j * KIN + k]
                                  : Whh[(size_t)j * LSTM_H + (k - KIN)];
        Wp[i] = __builtin_bit_cast(u16, (__bf16)v);
    }
}

// ---------------------------------------------------------------------------
// One layer step. Block = 128 rows x 128 gatecols; 8 waves (2m x 4n);
// wave = 64 rows x 32 cols (4 m-frags x 2 n-frags of 16x16x32 bf16 MFMA).
// B (weights) in VGPRs; A staged to LDS once (XOR-swizzled); barrier-free
// K loop. Epilogue stores are write-through (no L2 dirty data at boundary).
// ---------------------------------------------------------------------------
template<int KIN>
__device__ __forceinline__ void run_layer(
    const float* __restrict__ xf32,     // L0: X slice (f32), else nullptr
    const u16* __restrict__ hbelow,     // L1: h0 current; L0: unused
    const u16* __restrict__ hself,      // recurrent hidden (bf16)
    const u16* __restrict__ Wp,
    const float* __restrict__ bih, const float* __restrict__ bhh,
    u16* __restrict__ hout, float* __restrict__ latout,
    float* __restrict__ cst,
    int blk, char* smem, int tid)
{
    constexpr int NCH = (KIN + LSTM_H) / 32;
    constexpr bool IS_L0 = (KIN == 64);
    const int lane = tid & 63;
    const int w = tid >> 6;
    const int wm = w >> 2;            // 0..1
    const int wn = w & 3;             // 0..3
    const int l15 = lane & 15;
    const int q = lane >> 4;          // 0..3
    const int mb = blk >> 3;
    const int nb = blk & 7;
    const int b0 = mb * 128;

    // ---- B into registers (frag-packed, contiguous 16B loads) ----
    bf16x8 Breg[NCH][2];
    {
        const u16* wp = Wp + (size_t)((nb * 4 + wn) * NCH) * 1024 + lane * 8;
#pragma unroll
        for (int ch = 0; ch < NCH; ++ch)
#pragma unroll
            for (int nf = 0; nf < 2; ++nf)
                Breg[ch][nf] = *(const bf16x8*)(wp + (ch * 2 + nf) * 512);
    }

    // ---- c-state preload ----
    const int hcol = nb * 32 + wn * 8 + (l15 >> 1);
    const int rowA = wm * 64;
    float cp[4][4];
#pragma unroll
    for (int mf = 0; mf < 4; ++mf)
#pragma unroll
        for (int r = 0; r < 4; ++r)
            cp[mf][r] = cst[(size_t)(b0 + rowA + mf * 16 + q * 4 + r) * 256 + hcol];

    // ---- bias ----
    const int gpar = l15 & 1;
    const float b0a = bih[gpar * 256 + hcol] + bhh[gpar * 256 + hcol];
    const float b1a = bih[(2 + gpar) * 256 + hcol] + bhh[(2 + gpar) * 256 + hcol];

    // ---- stage A into LDS (swizzled source, linear dest) ----
    if (IS_L0) {
        // H region: [128 rows][512 B] at 0, via global_load_lds
#pragma unroll
        for (int i = 0; i < 8; ++i) {
            const int slot = i * 512 + tid;
            const int row = slot >> 5;
            const int so = (slot & 31) * 16;
            const int koff = so ^ ((row & 7) << 4);
            gload_lds16((const char*)hself + (size_t)(b0 + row) * 512 + koff,
                        smem + slot * 16);
        }
        // X region: [128 rows][128 B] at 65536, reg-convert f32->bf16
#pragma unroll
        for (int p = 0; p < 2; ++p) {
            const int slot = p * 512 + tid;
            const int row = slot >> 3;
            const int so = (slot & 7) * 16;
            const int koff = so ^ ((row & 7) << 4);
            const float* s = xf32 + (size_t)(b0 + row) * 64 + (koff >> 1);
            const float4 v0 = *(const float4*)s;
            const float4 v1 = *(const float4*)(s + 4);
            bf16x8 pk;
            pk[0] = (__bf16)v0.x; pk[1] = (__bf16)v0.y;
            pk[2] = (__bf16)v0.z; pk[3] = (__bf16)v0.w;
            pk[4] = (__bf16)v1.x; pk[5] = (__bf16)v1.y;
            pk[6] = (__bf16)v1.z; pk[7] = (__bf16)v1.w;
            *(bf16x8*)(smem + 65536 + slot * 16) = pk;
        }
    } else {
        // single region: [128 rows][1024 B]: first 512 = hbelow, rest = hself
#pragma unroll
        for (int i = 0; i < 16; ++i) {
            const int slot = i * 512 + tid;
            const int row = slot >> 6;
            const int so = (slot & 63) * 16;
            const int koff = so ^ ((row & 7) << 4);
            const char* src = (koff < 512)
                ? (const char*)hbelow + (size_t)(b0 + row) * 512 + koff
                : (const char*)hself + (size_t)(b0 + row) * 512 + (koff - 512);
            gload_lds16(src, smem + slot * 16);
        }
    }
    __syncthreads();

    // ---- barrier-free K loop ----
    f32x4 acc[4][2];
#pragma unroll
    for (int mf = 0; mf < 4; ++mf)
#pragma unroll
        for (int nf = 0; nf < 2; ++nf) acc[mf][nf] = f32x4{0.f, 0.f, 0.f, 0.f};

    const int qoff = q * 16;
    const int swzl = (l15 & 7) << 4;
#pragma unroll
    for (int ch = 0; ch < NCH; ++ch) {
        bf16x8 af[4];
#pragma unroll
        for (int mf = 0; mf < 4; ++mf) {
            const int row = rowA + mf * 16 + l15;
            const char* ap;
            if (IS_L0) {
                if (ch < 2)
                    ap = smem + 65536 + row * 128 + ((ch * 64 + qoff) ^ swzl);
                else
                    ap = smem + row * 512 + (((ch - 2) * 64 + qoff) ^ swzl);
            } else {
                ap = smem + row * 1024 + ((ch * 64 + qoff) ^ swzl);
            }
            af[mf] = *(const bf16x8*)ap;
        }
#pragma unroll
        for (int mf = 0; mf < 4; ++mf)
#pragma unroll
            for (int nf = 0; nf < 2; ++nf)
                acc[mf][nf] = __builtin_amdgcn_mfma_f32_16x16x32_bf16(
                    af[mf], Breg[ch][nf], acc[mf][nf], 0, 0, 0);
    }

    // ---- pointwise epilogue: gates via 2 shfl_xor(1); write-through stores.
    // Even/odd lane pairs compute identical (cn,hv); odd stores c, even
    // stores h (packed to u32 via shfl_xor(2)) or f32 latent at final slot.
#pragma unroll
    for (int mf = 0; mf < 4; ++mf) {
#pragma unroll
        for (int r = 0; r < 4; ++r) {
            const float a0 = acc[mf][0][r] + b0a;
            const float a1 = acc[mf][1][r] + b1a;
            const float p0 = __shfl_xor(a0, 1);
            const float p1 = __shfl_xor(a1, 1);
            const float gi = gpar ? p0 : a0;
            const float gf = gpar ? a0 : p0;
            const float gg = gpar ? p1 : a1;
            const float go = gpar ? a1 : p1;
            const float cn = fast_sigmoid(gf) * cp[mf][r]
                           + fast_sigmoid(gi) * fast_tanh(gg);
            const float hv = fast_sigmoid(go) * fast_tanh(cn);
            const int rowo = b0 + rowA + mf * 16 + q * 4 + r;
            const size_t oidx = (size_t)rowo * 256 + hcol;
            // pack h pair (hcol, hcol+1) across lanes l15, l15^2 (uniform shfl)
            const u16 hb = __builtin_bit_cast(u16, (__bf16)hv);
            const int pr = __shfl_xor((int)(u32)hb, 2);
            const u32 pk = ((u32)hb & 0xffffu) | (((u32)pr) << 16);
            if (gpar) {
                wt_store((u32*)&cst[oidx], __builtin_bit_cast(u32, cn));
            } else if (latout) {
                wt_store((u32*)&latout[oidx], __builtin_bit_cast(u32, hv));
            } else if ((l15 & 3) == 0) {
                wt_store((u32*)hout + ((size_t)rowo * 128 + (hcol >> 1)), pk);
            }
        }
    }
}

// Slot s: blocks 0..127 -> layer0 step s; 128..255 -> layer1 step s-1.
__global__ __launch_bounds__(512, 1) void lstm_slot(
    const float* __restrict__ xt,
    const u16* __restrict__ h0c, u16* __restrict__ h0n, float* __restrict__ c0,
    const u16* __restrict__ Wp0,
    const float* __restrict__ bih0, const float* __restrict__ bhh0,
    const u16* __restrict__ h1c, u16* __restrict__ h1n, float* __restrict__ c1,
    const u16* __restrict__ Wp1,
    const float* __restrict__ bih1, const float* __restrict__ bhh1,
    float* __restrict__ latout, int do0, int do1)
{
    extern __shared__ char smem[];
    const int tid = threadIdx.x;
    if (blockIdx.x < 128) {
        if (do0)
            run_layer<LSTM_HIN>(xt, nullptr, h0c, Wp0, bih0, bhh0,
                                h0n, nullptr, c0, blockIdx.x, smem, tid);
    } else {
        if (do1)
            run_layer<LSTM_H>(nullptr, h0c, h1c, Wp1, bih1, bhh1,
                              h1n, latout, c1, blockIdx.x - 128, smem, tid);
    }
}

// ---------------------------------------------------------------------------
// K-means: 32 fat blocks x 256 thr. Clusters LDS-resident as clT[j][k]
// (lane k -> bank k%32, conflict-free; row value broadcast). Per-block
// LDS-atomic partial sums -> global partials (no global atomics at all).
// ---------------------------------------------------------------------------
__global__ __launch_bounds__(256, 1) void assign_fused(
    const float* __restrict__ lat, const float* __restrict__ clusters,
    int* __restrict__ ids, float* __restrict__ partial, int* __restrict__ pcount)
{
    extern __shared__ char sm[];
    float* clT    = (float*)sm;                 // [j][k], 64 KB
    float* psum   = (float*)(sm + 65536);       // [k][h], 64 KB
    float* rowbuf = (float*)(sm + 131072);      // [wave][256], 4 KB
    int*   pcnt   = (int*)(sm + 135168);        // [64]

    const int tid = threadIdx.x;
    const int k = tid & 63;
    const int w = tid >> 6;

    for (int i = tid; i < 16384; i += 256) {
        const int kk = i >> 8, j = i & 255;
        clT[j * 64 + kk] = clusters[(size_t)kk * 256 + j];
        psum[i] = 0.f;
    }
    if (tid < 64) pcnt[tid] = 0;
    __syncthreads();

    float* rb = rowbuf + w * 256;
    const int rbase = (int)blockIdx.x * 64 + w * 16;
    for (int rr = 0; rr < 16; ++rr) {
        const int row = rbase + rr;
#pragma unroll
        for (int p = 0; p < 4; ++p)
            rb[p * 64 + k] = lat[(size_t)row * 256 + p * 64 + k];
        float d = 0.f;
#pragma unroll 8
        for (int j = 0; j < 256; ++j) {
            const float t = rb[j] - clT[j * 64 + k];
            d += t * t;
        }
        int idx = k;
        for (int off = 32; off > 0; off >>= 1) {
            const float od = __shfl_down(d, off, 64);
            const int   oi = __shfl_down(idx, off, 64);
            if (od < d || (od == d && oi < idx)) { d = od; idx = oi; }
        }
        const int best = __shfl(idx, 0, 64);
        if (k == 0) { ids[row] = best; atomicAdd(&pcnt[best], 1); }
#pragma unroll
        for (int p = 0; p < 4; ++p)
            atomicAdd(&psum[best * 256 + p * 64 + k], rb[p * 64 + k]);
    }
    __syncthreads();
    for (int i = tid; i < 16384; i += 256)
        partial[(size_t)blockIdx.x * 16384 + i] = psum[i];
    if (tid < 64) pcount[(size_t)blockIdx.x * 64 + tid] = pcnt[tid];
}

__global__ __launch_bounds__(256) void centroid_final2(
    const float* __restrict__ partial, const int* __restrict__ pcount,
    const float* __restrict__ clusters, float* __restrict__ upd)
{
    const int k = blockIdx.x;
    const int h = threadIdx.x;
    float s = 0.f;
    int c = 0;
    for (int b = 0; b < ASSIGN_BLOCKS; ++b) {
        s += partial[(size_t)b * 16384 + k * 256 + h];
        c += pcount[(size_t)b * 64 + k];
    }
    upd[(size_t)k * LSTM_H + h] = (c > 0)
        ? s / (float)c
        : clusters[(size_t)k * LSTM_H + h];
}

__global__ __launch_bounds__(256) void loss_kernel(
    const float* __restrict__ lat, const int* __restrict__ ids,
    const float* __restrict__ upd, float* __restrict__ out_loss)
{
    float p = 0.f;
    const int total = LSTM_B * LSTM_H;
    for (int idx = blockIdx.x * blockDim.x + threadIdx.x; idx < total;
         idx += gridDim.x * blockDim.x) {
        const int b = idx >> 8;
        const float d = lat[idx] - upd[(size_t)ids[b] * LSTM_H + (idx & 255)];
        p += d * d;
    }
    for (int off = 32; off > 0; off >>= 1) p += __shfl_down(p, off, 64);
    __shared__ float wsum[4];
    const int lane = threadIdx.x & 63, wid = threadIdx.x >> 6;
    if (lane == 0) wsum[wid] = p;
    __syncthreads();
    if (threadIdx.x == 0)
        atomicAdd(out_loss, HALF_BETA * (wsum[0] + wsum[1] + wsum[2] + wsum[3]));
}

// ---------------------------------------------------------------------------
extern "C" void kernel_launch(void* const* d_in, const int* in_sizes, int n_in,
                              void* d_out, int out_size, void* d_ws, size_t ws_size,
                              hipStream_t stream)
{
    const float* X     = (const float*)d_in[0];
    const float* Wih0  = (const float*)d_in[1];
    const float* Whh0  = (const float*)d_in[2];
    const float* bih0  = (const float*)d_in[3];
    const float* bhh0  = (const float*)d_in[4];
    const float* Wih1  = (const float*)d_in[5];
    const float* Whh1  = (const float*)d_in[6];
    const float* bih1  = (const float*)d_in[7];
    const float* bhh1  = (const float*)d_in[8];
    const float* clust = (const float*)d_in[9];

    float* out = (float*)d_out;
    char* base = (char*)d_ws;
    const size_t MB = 1u << 20;
    const size_t KB = 1024;

    u16* Wp0      = (u16*)(base + 0 * MB);              // 640 KB
    u16* Wp1      = (u16*)(base + 1 * MB);              // 1 MB
    u16* h0a      = (u16*)(base + 2 * MB);              // 1 MB each
    u16* h0b      = (u16*)(base + 3 * MB);
    u16* h1a      = (u16*)(base + 4 * MB);
    u16* h1b      = (u16*)(base + 5 * MB);
    float* c0     = (float*)(base + 6 * MB);            // 2 MB
    float* c1     = (float*)(base + 8 * MB);            // 2 MB
    float* partial= (float*)(base + 10 * MB);           // 2 MB (32 x 64 KB)
    float* upd    = (float*)(base + 12 * MB);           // 64 KB
    int* pcount   = (int*)(base + 12 * MB + 64 * KB);   // 8 KB
    int* ids      = (int*)(base + 12 * MB + 72 * KB);   // 8 KB

    const size_t BH = (size_t)LSTM_B * LSTM_H;

    hipMemsetAsync(h0a, 0, MB, stream);
    hipMemsetAsync(h1a, 0, MB, stream);
    hipMemsetAsync(c0, 0, 4 * MB, stream);              // c0+c1 contiguous
    hipMemsetAsync(out + BH, 0, sizeof(float), stream);

    pack_frag<LSTM_HIN><<<320, 256, 0, stream>>>(Wih0, Whh0, Wp0);
    pack_frag<LSTM_H>  <<<512, 256, 0, stream>>>(Wih1, Whh1, Wp1);

    hipFuncSetAttribute((const void*)lstm_slot,
                        hipFuncAttributeMaxDynamicSharedMemorySize, LDS_BYTES);
    hipFuncSetAttribute((const void*)assign_fused,
                        hipFuncAttributeMaxDynamicSharedMemorySize, ASSIGN_LDS);

    u16* h0c = h0a; u16* h0n = h0b;
    u16* h1c = h1a; u16* h1n = h1b;
    for (int s = 0; s <= LSTM_L; ++s) {
        const int do0 = (s < LSTM_L) ? 1 : 0;
        const int do1 = (s > 0) ? 1 : 0;
        const float* xt = do0 ? X + (size_t)s * LSTM_B * LSTM_HIN : nullptr;
        float* lat = (s == LSTM_L) ? out : nullptr;
        lstm_slot<<<256, 512, LDS_BYTES, stream>>>(
            xt, h0c, h0n, c0, Wp0, bih0, bhh0,
            h1c, h1n, c1, Wp1, bih1, bhh1, lat, do0, do1);
        if (do0) { u16* t = h0c; h0c = h0n; h0n = t; }
        if (do1) { u16* t = h1c; h1c = h1n; h1n = t; }
    }

    assign_fused<<<ASSIGN_BLOCKS, 256, ASSIGN_LDS, stream>>>(
        out, clust, ids, partial, pcount);
    centroid_final2<<<NCLUST, 256, 0, stream>>>(partial, pcount, clust, upd);
    loss_kernel<<<256, 256, 0, stream>>>(out, ids, upd, out + BH);
}

// Round 15
// 2620.408 us; speedup vs baseline: 5.9226x; 1.0133x over previous
//
#include <hip/hip_runtime.h>
#include <hip/hip_bf16.h>
#include <math.h>

typedef unsigned short u16;
typedef unsigned int u32;
typedef __attribute__((ext_vector_type(8))) __bf16 bf16x8;
typedef __attribute__((ext_vector_type(4))) float f32x4;

#define LSTM_L 200
#define LSTM_B 2048
#define LSTM_HIN 64
#define LSTM_H 256
#define NCLUST 64
#define HALF_BETA 0.05f
#define LDS_BYTES 131072
#define ASSIGN_LDS 135424   // clT 64K + psum 64K + rowbuf 4K + pcnt 256
#define ASSIGN_BLOCKS 64

__device__ __forceinline__ void gload_lds16(const void* g, void* l) {
    __builtin_amdgcn_global_load_lds(
        (__attribute__((address_space(1))) const void*)g,
        (__attribute__((address_space(3))) void*)l, 16, 0, 0);
}

__device__ __forceinline__ float fast_sigmoid(float x) {
    return __builtin_amdgcn_rcpf(1.f + __expf(-x));
}
__device__ __forceinline__ float fast_tanh(float x) {
    return 2.f * __builtin_amdgcn_rcpf(1.f + __expf(-2.f * x)) - 1.f;
}
// Write-through store (agent scope, relaxed): no dirty L2 line at boundary.
__device__ __forceinline__ void wt_store(u32* p, u32 v) {
    __hip_atomic_store(p, v, __ATOMIC_RELAXED, __HIP_MEMORY_SCOPE_AGENT);
}

// ---------------------------------------------------------------------------
// Weight pack into per-(nb,wn) fragment order (round-4 layout):
// i = ((((nb*4+wn)*NCH + ch)*2 + nf)*64 + lane)*8 + e
// j = (2*nf + (l15&1))*256 + nb*32 + wn*8 + (l15>>1); k = ch*32 + (lane>>4)*8 + e
// ---------------------------------------------------------------------------
template<int KIN>
__global__ __launch_bounds__(256) void pack_frag(
    const float* __restrict__ Wih, const float* __restrict__ Whh,
    u16* __restrict__ Wp)
{
    constexpr int NCH = (KIN + LSTM_H) / 32;
    const int total = 1024 * (KIN + LSTM_H);
    for (int i = blockIdx.x * 256 + threadIdx.x; i < total; i += gridDim.x * 256) {
        const int e = i & 7;
        int t = i >> 3;
        const int lane = t & 63; t >>= 6;
        const int nf = t & 1;    t >>= 1;
        const int ch = t % NCH;  t /= NCH;
        const int wn = t & 3;
        const int nb = t >> 2;
        const int l15 = lane & 15;
        const int j = (2 * nf + (l15 & 1)) * 256 + nb * 32 + wn * 8 + (l15 >> 1);
        const int k = ch * 32 + ((lane >> 4) << 3) + e;
        const float v = (k < KIN) ? Wih[(size_t)j * KIN + k]
                                  : Whh[(size_t)j * LSTM_H + (k - KIN)];
        Wp[i] = __builtin_bit_cast(u16, (__bf16)v);
    }
}

// ---------------------------------------------------------------------------
// One layer step. Block = 128 rows x 128 gatecols; 8 waves (2m x 4n);
// wave = 64 rows x 32 cols (4 m-frags x 2 n-frags of 16x16x32 bf16 MFMA).
// B (weights) in VGPRs; A staged to LDS once (XOR-swizzled); barrier-free
// K loop; write-through epilogue stores.
// ---------------------------------------------------------------------------
template<int KIN>
__device__ __forceinline__ void run_layer(
    const float* __restrict__ xf32,     // L0: X slice (f32), else nullptr
    const u16* __restrict__ hbelow,     // L1: h0 current; L0: unused
    const u16* __restrict__ hself,      // recurrent hidden (bf16)
    const u16* __restrict__ Wp,
    const float* __restrict__ bih, const float* __restrict__ bhh,
    u16* __restrict__ hout, float* __restrict__ latout,
    float* __restrict__ cst,
    int blk, char* smem, int tid)
{
    constexpr int NCH = (KIN + LSTM_H) / 32;
    constexpr bool IS_L0 = (KIN == 64);
    const int lane = tid & 63;
    const int w = tid >> 6;
    const int wm = w >> 2;            // 0..1
    const int wn = w & 3;             // 0..3
    const int l15 = lane & 15;
    const int q = lane >> 4;          // 0..3
    const int mb = blk >> 3;
    const int nb = blk & 7;
    const int b0 = mb * 128;

    // ---- B into registers (frag-packed, contiguous 16B loads) ----
    bf16x8 Breg[NCH][2];
    {
        const u16* wp = Wp + (size_t)((nb * 4 + wn) * NCH) * 1024 + lane * 8;
#pragma unroll
        for (int ch = 0; ch < NCH; ++ch)
#pragma unroll
            for (int nf = 0; nf < 2; ++nf)
                Breg[ch][nf] = *(const bf16x8*)(wp + (ch * 2 + nf) * 512);
    }

    // ---- c-state preload ----
    const int hcol = nb * 32 + wn * 8 + (l15 >> 1);
    const int rowA = wm * 64;
    float cp[4][4];
#pragma unroll
    for (int mf = 0; mf < 4; ++mf)
#pragma unroll
        for (int r = 0; r < 4; ++r)
            cp[mf][r] = cst[(size_t)(b0 + rowA + mf * 16 + q * 4 + r) * 256 + hcol];

    // ---- bias ----
    const int gpar = l15 & 1;
    const float b0a = bih[gpar * 256 + hcol] + bhh[gpar * 256 + hcol];
    const float b1a = bih[(2 + gpar) * 256 + hcol] + bhh[(2 + gpar) * 256 + hcol];

    // ---- stage A into LDS (swizzled source, linear dest) ----
    if (IS_L0) {
        // H region: [128 rows][512 B] at 0, via global_load_lds
#pragma unroll
        for (int i = 0; i < 8; ++i) {
            const int slot = i * 512 + tid;
            const int row = slot >> 5;
            const int so = (slot & 31) * 16;
            const int koff = so ^ ((row & 7) << 4);
            gload_lds16((const char*)hself + (size_t)(b0 + row) * 512 + koff,
                        smem + slot * 16);
        }
        // X region: [128 rows][128 B] at 65536, reg-convert f32->bf16
#pragma unroll
        for (int p = 0; p < 2; ++p) {
            const int slot = p * 512 + tid;
            const int row = slot >> 3;
            const int so = (slot & 7) * 16;
            const int koff = so ^ ((row & 7) << 4);
            const float* s = xf32 + (size_t)(b0 + row) * 64 + (koff >> 1);
            const float4 v0 = *(const float4*)s;
            const float4 v1 = *(const float4*)(s + 4);
            bf16x8 pk;
            pk[0] = (__bf16)v0.x; pk[1] = (__bf16)v0.y;
            pk[2] = (__bf16)v0.z; pk[3] = (__bf16)v0.w;
            pk[4] = (__bf16)v1.x; pk[5] = (__bf16)v1.y;
            pk[6] = (__bf16)v1.z; pk[7] = (__bf16)v1.w;
            *(bf16x8*)(smem + 65536 + slot * 16) = pk;
        }
    } else {
        // single region: [128 rows][1024 B]: first 512 = hbelow, rest = hself
#pragma unroll
        for (int i = 0; i < 16; ++i) {
            const int slot = i * 512 + tid;
            const int row = slot >> 6;
            const int so = (slot & 63) * 16;
            const int koff = so ^ ((row & 7) << 4);
            const char* src = (koff < 512)
                ? (const char*)hbelow + (size_t)(b0 + row) * 512 + koff
                : (const char*)hself + (size_t)(b0 + row) * 512 + (koff - 512);
            gload_lds16(src, smem + slot * 16);
        }
    }
    __syncthreads();

    // ---- barrier-free K loop ----
    f32x4 acc[4][2];
#pragma unroll
    for (int mf = 0; mf < 4; ++mf)
#pragma unroll
        for (int nf = 0; nf < 2; ++nf) acc[mf][nf] = f32x4{0.f, 0.f, 0.f, 0.f};

    const int qoff = q * 16;
    const int swzl = (l15 & 7) << 4;
#pragma unroll
    for (int ch = 0; ch < NCH; ++ch) {
        bf16x8 af[4];
#pragma unroll
        for (int mf = 0; mf < 4; ++mf) {
            const int row = rowA + mf * 16 + l15;
            const char* ap;
            if (IS_L0) {
                if (ch < 2)
                    ap = smem + 65536 + row * 128 + ((ch * 64 + qoff) ^ swzl);
                else
                    ap = smem + row * 512 + (((ch - 2) * 64 + qoff) ^ swzl);
            } else {
                ap = smem + row * 1024 + ((ch * 64 + qoff) ^ swzl);
            }
            af[mf] = *(const bf16x8*)ap;
        }
#pragma unroll
        for (int mf = 0; mf < 4; ++mf)
#pragma unroll
            for (int nf = 0; nf < 2; ++nf)
                acc[mf][nf] = __builtin_amdgcn_mfma_f32_16x16x32_bf16(
                    af[mf], Breg[ch][nf], acc[mf][nf], 0, 0, 0);
    }

    // ---- pointwise epilogue: gates via 2 shfl_xor(1); write-through stores.
#pragma unroll
    for (int mf = 0; mf < 4; ++mf) {
#pragma unroll
        for (int r = 0; r < 4; ++r) {
            const float a0 = acc[mf][0][r] + b0a;
            const float a1 = acc[mf][1][r] + b1a;
            const float p0 = __shfl_xor(a0, 1);
            const float p1 = __shfl_xor(a1, 1);
            const float gi = gpar ? p0 : a0;
            const float gf = gpar ? a0 : p0;
            const float gg = gpar ? p1 : a1;
            const float go = gpar ? a1 : p1;
            const float cn = fast_sigmoid(gf) * cp[mf][r]
                           + fast_sigmoid(gi) * fast_tanh(gg);
            const float hv = fast_sigmoid(go) * fast_tanh(cn);
            const int rowo = b0 + rowA + mf * 16 + q * 4 + r;
            const size_t oidx = (size_t)rowo * 256 + hcol;
            // pack h pair (hcol, hcol+1) across lanes l15, l15^2 (uniform shfl)
            const u16 hb = __builtin_bit_cast(u16, (__bf16)hv);
            const int pr = __shfl_xor((int)(u32)hb, 2);
            const u32 pk = ((u32)hb & 0xffffu) | (((u32)pr) << 16);
            if (gpar) {
                wt_store((u32*)&cst[oidx], __builtin_bit_cast(u32, cn));
            } else if (latout) {
                wt_store((u32*)&latout[oidx], __builtin_bit_cast(u32, hv));
            } else if ((l15 & 3) == 0) {
                wt_store((u32*)hout + ((size_t)rowo * 128 + (hcol >> 1)), pk);
            }
        }
    }
}

// Slot s: blocks 0..127 -> layer0 step s; 128..255 -> layer1 step s-1.
__global__ __launch_bounds__(512, 1) void lstm_slot(
    const float* __restrict__ xt,
    const u16* __restrict__ h0c, u16* __restrict__ h0n, float* __restrict__ c0,
    const u16* __restrict__ Wp0,
    const float* __restrict__ bih0, const float* __restrict__ bhh0,
    const u16* __restrict__ h1c, u16* __restrict__ h1n, float* __restrict__ c1,
    const u16* __restrict__ Wp1,
    const float* __restrict__ bih1, const float* __restrict__ bhh1,
    float* __restrict__ latout, int do0, int do1)
{
    extern __shared__ char smem[];
    const int tid = threadIdx.x;
    if (blockIdx.x < 128) {
        if (do0)
            run_layer<LSTM_HIN>(xt, nullptr, h0c, Wp0, bih0, bhh0,
                                h0n, nullptr, c0, blockIdx.x, smem, tid);
    } else {
        if (do1)
            run_layer<LSTM_H>(nullptr, h0c, h1c, Wp1, bih1, bhh1,
                              h1n, latout, c1, blockIdx.x - 128, smem, tid);
    }
}

// ---------------------------------------------------------------------------
// K-means: 64 blocks x 256 thr, 32 rows/block = 4 waves x 8 rows. Clusters
// LDS-resident as clT[j][k]; distance dep-chain split into 4 partials;
// per-block LDS-atomic partial sums -> global partials.
// ---------------------------------------------------------------------------
__global__ __launch_bounds__(256, 1) void assign_fused(
    const float* __restrict__ lat, const float* __restrict__ clusters,
    int* __restrict__ ids, float* __restrict__ partial, int* __restrict__ pcount)
{
    extern __shared__ char sm[];
    float* clT    = (float*)sm;                 // [j][k], 64 KB
    float* psum   = (float*)(sm + 65536);       // [k][h], 64 KB
    float* rowbuf = (float*)(sm + 131072);      // [wave][256], 4 KB
    int*   pcnt   = (int*)(sm + 135168);        // [64]

    const int tid = threadIdx.x;
    const int k = tid & 63;
    const int w = tid >> 6;

    for (int i = tid; i < 16384; i += 256) {
        const int kk = i >> 8, j = i & 255;
        clT[j * 64 + kk] = clusters[(size_t)kk * 256 + j];
        psum[i] = 0.f;
    }
    if (tid < 64) pcnt[tid] = 0;
    __syncthreads();

    float* rb = rowbuf + w * 256;
    const int rbase = (int)blockIdx.x * 32 + w * 8;   // 4 waves x 8 rows = 32
    for (int rr = 0; rr < 8; ++rr) {
        const int row = rbase + rr;
#pragma unroll
        for (int p = 0; p < 4; ++p)
            rb[p * 64 + k] = lat[(size_t)row * 256 + p * 64 + k];
        // 4 independent partial accumulators -> dep chain 256 -> 64 FMA deep
        float d0 = 0.f, d1 = 0.f, d2 = 0.f, d3 = 0.f;
#pragma unroll 4
        for (int j = 0; j < 256; j += 4) {
            const float t0 = rb[j + 0] - clT[(j + 0) * 64 + k];
            const float t1 = rb[j + 1] - clT[(j + 1) * 64 + k];
            const float t2 = rb[j + 2] - clT[(j + 2) * 64 + k];
            const float t3 = rb[j + 3] - clT[(j + 3) * 64 + k];
            d0 += t0 * t0; d1 += t1 * t1; d2 += t2 * t2; d3 += t3 * t3;
        }
        float d = (d0 + d1) + (d2 + d3);
        int idx = k;
        for (int off = 32; off > 0; off >>= 1) {
            const float od = __shfl_down(d, off, 64);
            const int   oi = __shfl_down(idx, off, 64);
            if (od < d || (od == d && oi < idx)) { d = od; idx = oi; }
        }
        const int best = __shfl(idx, 0, 64);
        if (k == 0) { ids[row] = best; atomicAdd(&pcnt[best], 1); }
#pragma unroll
        for (int p = 0; p < 4; ++p)
            atomicAdd(&psum[best * 256 + p * 64 + k], rb[p * 64 + k]);
    }
    __syncthreads();
    for (int i = tid; i < 16384; i += 256)
        partial[(size_t)blockIdx.x * 16384 + i] = psum[i];
    if (tid < 64) pcount[(size_t)blockIdx.x * 64 + tid] = pcnt[tid];
}

__global__ __launch_bounds__(256) void centroid_final2(
    const float* __restrict__ partial, const int* __restrict__ pcount,
    const float* __restrict__ clusters, float* __restrict__ upd)
{
    const int k = blockIdx.x;
    const int h = threadIdx.x;
    float s = 0.f;
    int c = 0;
    for (int b = 0; b < ASSIGN_BLOCKS; ++b) {
        s += partial[(size_t)b * 16384 + k * 256 + h];
        c += pcount[(size_t)b * 64 + k];
    }
    upd[(size_t)k * LSTM_H + h] = (c > 0)
        ? s / (float)c
        : clusters[(size_t)k * LSTM_H + h];
}

__global__ __launch_bounds__(256) void loss_kernel(
    const float* __restrict__ lat, const int* __restrict__ ids,
    const float* __restrict__ upd, float* __restrict__ out_loss)
{
    float p = 0.f;
    const int total = LSTM_B * LSTM_H;
    for (int idx = blockIdx.x * blockDim.x + threadIdx.x; idx < total;
         idx += gridDim.x * blockDim.x) {
        const int b = idx >> 8;
        const float d = lat[idx] - upd[(size_t)ids[b] * LSTM_H + (idx & 255)];
        p += d * d;
    }
    for (int off = 32; off > 0; off >>= 1) p += __shfl_down(p, off, 64);
    __shared__ float wsum[4];
    const int lane = threadIdx.x & 63, wid = threadIdx.x >> 6;
    if (lane == 0) wsum[wid] = p;
    __syncthreads();
    if (threadIdx.x == 0)
        atomicAdd(out_loss, HALF_BETA * (wsum[0] + wsum[1] + wsum[2] + wsum[3]));
}

// ---------------------------------------------------------------------------
extern "C" void kernel_launch(void* const* d_in, const int* in_sizes, int n_in,
                              void* d_out, int out_size, void* d_ws, size_t ws_size,
                              hipStream_t stream)
{
    const float* X     = (const float*)d_in[0];
    const float* Wih0  = (const float*)d_in[1];
    const float* Whh0  = (const float*)d_in[2];
    const float* bih0  = (const float*)d_in[3];
    const float* bhh0  = (const float*)d_in[4];
    const float* Wih1  = (const float*)d_in[5];
    const float* Whh1  = (const float*)d_in[6];
    const float* bih1  = (const float*)d_in[7];
    const float* bhh1  = (const float*)d_in[8];
    const float* clust = (const float*)d_in[9];

    float* out = (float*)d_out;
    char* base = (char*)d_ws;
    const size_t MB = 1u << 20;
    const size_t KB = 1024;

    u16* Wp0      = (u16*)(base + 0 * MB);              // 640 KB
    u16* Wp1      = (u16*)(base + 1 * MB);              // 1 MB
    u16* h0a      = (u16*)(base + 2 * MB);              // 1 MB each
    u16* h0b      = (u16*)(base + 3 * MB);
    u16* h1a      = (u16*)(base + 4 * MB);
    u16* h1b      = (u16*)(base + 5 * MB);
    float* c0     = (float*)(base + 6 * MB);            // 2 MB
    float* c1     = (float*)(base + 8 * MB);            // 2 MB
    // partial ALIASES c0/c1 (4 MB): c-states are dead once assign_fused runs.
    float* partial= (float*)(base + 6 * MB);            // 4 MB (64 x 64 KB)
    float* upd    = (float*)(base + 10 * MB);           // 64 KB
    int* pcount   = (int*)(base + 10 * MB + 64 * KB);   // 16 KB
    int* ids      = (int*)(base + 10 * MB + 80 * KB);   // 8 KB

    const size_t BH = (size_t)LSTM_B * LSTM_H;

    hipMemsetAsync(h0a, 0, MB, stream);
    hipMemsetAsync(h1a, 0, MB, stream);
    hipMemsetAsync(c0, 0, 4 * MB, stream);              // c0+c1 contiguous
    hipMemsetAsync(out + BH, 0, sizeof(float), stream);

    pack_frag<LSTM_HIN><<<320, 256, 0, stream>>>(Wih0, Whh0, Wp0);
    pack_frag<LSTM_H>  <<<512, 256, 0, stream>>>(Wih1, Whh1, Wp1);

    hipFuncSetAttribute((const void*)lstm_slot,
                        hipFuncAttributeMaxDynamicSharedMemorySize, LDS_BYTES);
    hipFuncSetAttribute((const void*)assign_fused,
                        hipFuncAttributeMaxDynamicSharedMemorySize, ASSIGN_LDS);

    u16* h0c = h0a; u16* h0n = h0b;
    u16* h1c = h1a; u16* h1n = h1b;
    for (int s = 0; s <= LSTM_L; ++s) {
        const int do0 = (s < LSTM_L) ? 1 : 0;
        const int do1 = (s > 0) ? 1 : 0;
        const float* xt = do0 ? X + (size_t)s * LSTM_B * LSTM_HIN : nullptr;
        float* lat = (s == LSTM_L) ? out : nullptr;
        lstm_slot<<<256, 512, LDS_BYTES, stream>>>(
            xt, h0c, h0n, c0, Wp0, bih0, bhh0,
            h1c, h1n, c1, Wp1, bih1, bhh1, lat, do0, do1);
        if (do0) { u16* t = h0c; h0c = h0n; h0n = t; }
        if (do1) { u16* t = h1c; h1c = h1n; h1n = t; }
    }

    assign_fused<<<ASSIGN_BLOCKS, 256, ASSIGN_LDS, stream>>>(
        out, clust, ids, partial, pcount);
    centroid_final2<<<NCLUST, 256, 0, stream>>>(partial, pcount, clust, upd);
    loss_kernel<<<256, 256, 0, stream>>>(out, ids, upd, out + BH);
}